// Round 19
// baseline (115.249 us; speedup 1.0000x reference)
//
#include <hip/hip_runtime.h>

#define S_LEN 4096
#define DMODEL 1024
#define NHEADS 16
#define DKH 64
#define WIN 256
#define GTOK 64
#define NSPLIT 8

typedef unsigned short u16t;
typedef __attribute__((ext_vector_type(8))) short short8;
typedef __attribute__((ext_vector_type(4))) float f32x4;

__device__ __forceinline__ u16t f2bf(float x) {
  union { float f; unsigned int u; } v; v.f = x;
  unsigned int r = v.u + 0x7FFFu + ((v.u >> 16) & 1u);
  return (u16t)(r >> 16);
}

__device__ __forceinline__ unsigned int cvtpk(float lo, float hi) {
  unsigned int r;
  asm("v_cvt_pk_bf16_f32 %0, %1, %2" : "=v"(r) : "v"(lo), "v"(hi));
  return r;
}

__device__ __forceinline__ void gload_lds16(const u16t* g, u16t* l) {
  __builtin_amdgcn_global_load_lds(
      (const __attribute__((address_space(1))) void*)g,
      (__attribute__((address_space(3))) void*)l, 16, 0, 0);
}

// ---------------- fused fp32 -> bf16 convert (all 7 tensors, one launch) -------
__global__ void cvt_all(const float* __restrict__ s0, const float* __restrict__ s1,
                        const float* __restrict__ s2, const float* __restrict__ s3,
                        const float* __restrict__ s4, const float* __restrict__ s5,
                        const float* __restrict__ s6,
                        u16t* __restrict__ d0, u16t* __restrict__ d1,
                        u16t* __restrict__ d2, u16t* __restrict__ d3,
                        u16t* __restrict__ d4, u16t* __restrict__ d5,
                        u16t* __restrict__ d6) {
  size_t i = (size_t)blockIdx.x * 1024 + threadIdx.x * 4;
  const float* s; u16t* d; size_t local;
  if (i < ((size_t)4 << 20)) {
    int which = (int)(i >> 20);
    local = i & ((1u << 20) - 1);
    s = which == 0 ? s0 : which == 1 ? s1 : which == 2 ? s2 : s3;
    d = which == 0 ? d0 : which == 1 ? d1 : which == 2 ? d2 : d3;
  } else {
    size_t j = i - ((size_t)4 << 20);
    int which = (int)(j >> 22);
    local = j & ((1u << 22) - 1);
    s = which == 0 ? s4 : which == 1 ? s5 : s6;
    d = which == 0 ? d4 : which == 1 ? d5 : d6;
  }
  float4 f = *(const float4*)(s + local);
  unsigned int lo = (unsigned int)f2bf(f.x) | ((unsigned int)f2bf(f.y) << 16);
  unsigned int hi = (unsigned int)f2bf(f.z) | ((unsigned int)f2bf(f.w) << 16);
  *(uint2*)(d + local) = make_uint2(lo, hi);
}

// ---------------- bf16 GEMM body: Y = A @ B^T + bias, * alpha -------------------
#define BN 128
#define GBK 64

template<int OUT_F32, int BMT, int BIAS_ROW>
__device__ __forceinline__
void gemm_body(u16t* __restrict__ smem,
               const u16t* __restrict__ A, const u16t* __restrict__ B,
               const float* __restrict__ bias, void* __restrict__ Y,
               int N, int K, float alpha, int m0, int n0)
{
  constexpr int MF = BMT / 32;
  constexpr int CA_ISS = BMT * 2 / 64;
  constexpr int TILE = (BMT + BN) * GBK;

  const int tid = threadIdx.x;
  const int lane = tid & 63;
  const int lr = lane & 15, lg = lane >> 4;
  const int w = tid >> 6;
  const int wm = (w >> 1) * (MF * 16), wn = (w & 1) * 64;

  f32x4 acc[MF][4] = {};
  const int nk = K / GBK;

  auto stage = [&](int buf, int kt) {
    u16t* sA = smem + buf * TILE;
    u16t* sB = sA + BMT * GBK;
#pragma unroll
    for (int i = 0; i < CA_ISS; ++i) {
      int c0 = w * (BMT * 2) + i * 64;
      int c = c0 + lane;
      int row = c >> 3, g = (c & 7) ^ (row & 7);
      gload_lds16(A + (size_t)(m0 + row) * K + kt * GBK + g * 8, sA + (size_t)c0 * 8);
    }
#pragma unroll
    for (int i = 0; i < 4; ++i) {
      int c0 = w * 256 + i * 64;
      int c = c0 + lane;
      int row = c >> 3, g = (c & 7) ^ (row & 7);
      gload_lds16(B + (size_t)(n0 + row) * K + kt * GBK + g * 8, sB + (size_t)c0 * 8);
    }
  };

  stage(0, 0);
  __syncthreads();

  for (int kt = 0; kt < nk; ++kt) {
    const int buf = kt & 1;
    if (kt + 1 < nk) stage(buf ^ 1, kt + 1);

    const u16t* sA = smem + buf * TILE;
    const u16t* sB = sA + BMT * GBK;

    short8 af[MF][2], bf[4][2];
#pragma unroll
    for (int mf = 0; mf < MF; ++mf)
#pragma unroll
      for (int kk = 0; kk < 2; ++kk) {
        int s = ((kk * 4 + lg) ^ (lr & 7));
        af[mf][kk] = *(const short8*)&sA[(wm + mf * 16 + lr) * GBK + s * 8];
      }
#pragma unroll
    for (int nf = 0; nf < 4; ++nf)
#pragma unroll
      for (int kk = 0; kk < 2; ++kk) {
        int s = ((kk * 4 + lg) ^ (lr & 7));
        bf[nf][kk] = *(const short8*)&sB[(wn + nf * 16 + lr) * GBK + s * 8];
      }
    __builtin_amdgcn_s_setprio(1);
#pragma unroll
    for (int kk = 0; kk < 2; ++kk)
#pragma unroll
      for (int mf = 0; mf < MF; ++mf)
#pragma unroll
        for (int nf = 0; nf < 4; ++nf)
          acc[mf][nf] = __builtin_amdgcn_mfma_f32_16x16x32_bf16(af[mf][kk], bf[nf][kk], acc[mf][nf], 0, 0, 0);
    __builtin_amdgcn_s_setprio(0);

    if (kt + 1 < nk) __syncthreads();
  }

#pragma unroll
  for (int nf = 0; nf < 4; ++nf) {
    int col = n0 + wn + nf * 16 + lr;
    float bvc = BIAS_ROW ? 0.f : bias[col];
#pragma unroll
    for (int mf = 0; mf < MF; ++mf)
#pragma unroll
      for (int r = 0; r < 4; ++r) {
        int row = m0 + wm + mf * 16 + lg * 4 + r;
        float bv = BIAS_ROW ? bias[row] : bvc;
        float v = (acc[mf][nf][r] + bv) * alpha;
        if (OUT_F32) ((float*)Y)[(size_t)row * N + col] = v;
        else         ((u16t*)Y)[(size_t)row * N + col] = f2bf(v);
      }
  }
}

// fused Q/K/V projection: 768 blocks (1D), bijective XCD swizzle (96 blocks/XCD)
#define QSCALE 0.18033688011112042f
__global__ __launch_bounds__(256)
void gemm_qkv(const u16t* __restrict__ xq, const u16t* __restrict__ xk, const u16t* __restrict__ xv,
              const u16t* __restrict__ wq, const u16t* __restrict__ wk, const u16t* __restrict__ wv,
              const float* __restrict__ bq, const float* __restrict__ bk, const float* __restrict__ bv,
              u16t* __restrict__ Qp, u16t* __restrict__ Kp, u16t* __restrict__ Vt)
{
  __shared__ __align__(16) u16t smem[2 * (128 + 128) * GBK];  // 64 KB

  int b = blockIdx.x;
  int wid = (b & 7) * 96 + (b >> 3);
  int z = wid >> 8;
  int rem = wid & 255;
  if (z == 0) {
    gemm_body<0, 128, 0>(smem, xq, wq, bq, Qp, DMODEL, DMODEL, QSCALE, (rem >> 3) * 128, (rem & 7) * BN);
  } else if (z == 1) {
    gemm_body<0, 128, 0>(smem, xk, wk, bk, Kp, DMODEL, DMODEL, 1.0f, (rem >> 3) * 128, (rem & 7) * BN);
  } else {
    gemm_body<0, 128, 1>(smem, wv, xv, bv, Vt, S_LEN, DMODEL, 1.0f, (rem & 7) * 128, (rem >> 3) * BN);
  }
}

__global__ __launch_bounds__(256)
void gemm_o(const u16t* __restrict__ A, const u16t* __restrict__ B,
            const float* __restrict__ bias, float* __restrict__ Y)
{
  __shared__ __align__(16) u16t smem[2 * (64 + 128) * GBK];  // 48 KB

  int b = blockIdx.x;
  int wid = (b & 7) * 64 + (b >> 3);
  int my = wid >> 3, mx = wid & 7;
  gemm_body<1, 64, 0>(smem, A, B, bias, Y, DMODEL, DMODEL, 1.0f, my * 64, mx * BN);
}

// ---------------- flash-style sparse attention: 128 q-rows / block (8 waves) ----
// Staged K/V tile now serves 128 q-rows: staging bytes, gload issues, and
// barriers per q-row HALVE (tiles/head ~636 -> ~340). 48 KB LDS -> 3 blocks/CU
// (24 waves). Per-wave inner code identical to the proven 4-wave version.
// grid: 640 = 16 heads x (32 windowed + NSPLIT) with bijective XCD swizzle.
__global__ __launch_bounds__(512)
void attn_kernel(const u16t* __restrict__ Qp, const u16t* __restrict__ Kp,
                 const u16t* __restrict__ Vt, u16t* __restrict__ AO,
                 float* __restrict__ pacc, float* __restrict__ pml)
{
  __shared__ __align__(16) u16t sK[2][64 * 64];   // 16 KB
  __shared__ __align__(16) u16t sV[2][64 * 64];   // 16 KB
  __shared__ __align__(16) u16t sP[8][16 * 64];   // 16 KB

  const int b = blockIdx.x;                    // 0..639
  const int wid = (b & 7) * 80 + (b >> 3);     // XCD-contiguous work id
  const int h = wid / 40;
  const int x = wid % 40;                      // 0..31 windowed, 32..39 split

  const int tid = threadIdx.x, w = tid >> 6, lane = tid & 63;
  const int lr = lane & 15, lg = lane >> 4;

  const bool windowed = (x < 32);
  // windowed block x covers q-blocks [qbl, qbh] (qbh = qbl+1 except x=31)
  const int qbl = windowed ? (2 * x + 1) : 0;
  const int qbh = windowed ? ((x == 31) ? 63 : 2 * x + 2) : 0;
  const int split = windowed ? 0 : (x - 32);

  // wave -> q rows. x=31 has only 64 rows (4 waves); split has 64 rows.
  const bool active = windowed ? !(x == 31 && w >= 4) : (w < 4);
  const int wq = windowed ? ((x == 31) ? (w & 3) : w) : (w & 3);
  const int qw = qbl * 64 + wq * 16;

  short8 qf[2];
#pragma unroll
  for (int kk = 0; kk < 2; ++kk)
    qf[kk] = *(const short8*)(Qp + (size_t)(qw + lr) * DMODEL + h * DKH + kk * 32 + lg * 8);

  f32x4 acc[4] = {};
  float m_run = -1e30f;   // group-uniform (per q-row = lr group) by induction
  float l_run = 0.f;      // per-lane partial sum; reduced once at epilogue

  int lo = 1, nkv;
  if (windowed) {
    lo = (qbl - 4 < 1) ? 1 : qbl - 4;
    int hi = (qbh + 4 > 63) ? 63 : qbh + 4;
    nkv = hi - lo + 2;  // {0} ∪ [lo..hi]
  } else {
    nkv = 64 / NSPLIT;
  }

#define KVB(idx) (windowed ? ((idx) == 0 ? 0 : lo + (idx) - 1) : (split * (64 / NSPLIT) + (idx)))

  // 512 threads stage one 64x64 K tile + V^T tile: 1 issue each per tensor
  auto stage = [&](int buf, int kvb) {
    int kv0 = kvb * 64;
    int c = tid;
    int row = c >> 3, g = (c & 7) ^ (row & 7);
    gload_lds16(Kp + (size_t)(kv0 + row) * DMODEL + h * DKH + g * 8, &sK[buf][c * 8]);
    gload_lds16(Vt + (size_t)(h * DKH + row) * S_LEN + kv0 + g * 8, &sV[buf][c * 8]);
  };

  stage(0, KVB(0));
  __syncthreads();

  for (int idx = 0; idx < nkv; ++idx) {
    const int buf = idx & 1;
    const int kvb = KVB(idx);
    const int kv0 = kvb * 64;

    if (idx + 1 < nkv) stage(buf ^ 1, KVB(idx + 1));

    // S^T = K Q^T: sacc[nf][r] = S[k = kv0 + nf*16 + lg*4 + r][q = qw + lr]
    f32x4 sacc[4] = {};
    __builtin_amdgcn_s_setprio(1);
#pragma unroll
    for (int kk = 0; kk < 2; ++kk)
#pragma unroll
      for (int nf = 0; nf < 4; ++nf) {
        int s = ((kk * 4 + lg) ^ (lr & 7));
        short8 kf = *(const short8*)&sK[buf][(nf * 16 + lr) * 64 + s * 8];
        sacc[nf] = __builtin_amdgcn_mfma_f32_16x16x32_bf16(kf, qf[kk], sacc[nf], 0, 0, 0);
      }
    __builtin_amdgcn_s_setprio(0);

    // mask only tiles where some |q-k| can exceed WIN (4 edge tiles), never tile 0
    if (windowed && kvb > 0 && (kvb <= qbh - 4 || kvb >= qbl + 4)) {
      int qg = qw + lr;
#pragma unroll
      for (int nf = 0; nf < 4; ++nf)
#pragma unroll
        for (int r = 0; r < 4; ++r) {
          int sg = kv0 + nf * 16 + lg * 4 + r;
          int diff = qg - sg; if (diff < 0) diff = -diff;
          if (diff > WIN) sacc[nf][r] = -1e30f;
        }
    }

    // per-lane local max (no cross-lane) via max3-friendly triples
    float rm0 = fmaxf(fmaxf(sacc[0][0], sacc[0][1]), sacc[0][2]);
    float rm1 = fmaxf(fmaxf(sacc[0][3], sacc[1][0]), sacc[1][1]);
    float rm2 = fmaxf(fmaxf(sacc[1][2], sacc[1][3]), sacc[2][0]);
    float rm3 = fmaxf(fmaxf(sacc[2][1], sacc[2][2]), sacc[2][3]);
    float rm4 = fmaxf(fmaxf(sacc[3][0], sacc[3][1]), sacc[3][2]);
    float rm = fmaxf(fmaxf(rm0, rm1), fmaxf(fmaxf(rm2, rm3), fmaxf(rm4, sacc[3][3])));

    // gated max-reduce + defer-max (T13)
    if (!__all(rm <= m_run + 11.0f)) {
      rm = fmaxf(rm, __shfl_xor(rm, 16));
      rm = fmaxf(rm, __shfl_xor(rm, 32));
      float mnew = fmaxf(m_run, rm);
      float corr = exp2f(m_run - mnew);
      m_run = mnew;
      l_run *= corr;
      float cq[4];
#pragma unroll
      for (int r = 0; r < 4; ++r) cq[r] = __shfl(corr, lg * 4 + r);
#pragma unroll
      for (int nf = 0; nf < 4; ++nf)
#pragma unroll
        for (int r = 0; r < 4; ++r) acc[nf][r] *= cq[r];
    }

    float p[4][4];
    float rs = 0.f;
#pragma unroll
    for (int nf = 0; nf < 4; ++nf)
#pragma unroll
      for (int r = 0; r < 4; ++r) {
        float e = exp2f(sacc[nf][r] - m_run);
        p[nf][r] = e;
        rs += e;
      }
    l_run += rs;

    // P -> LDS via v_cvt_pk_bf16_f32; stride 64 with XOR-block swizzle
#pragma unroll
    for (int nf = 0; nf < 4; ++nf) {
      unsigned int lo32 = cvtpk(p[nf][0], p[nf][1]);
      unsigned int hi32 = cvtpk(p[nf][2], p[nf][3]);
      int blk = (nf * 2 + (lg >> 1)) ^ (lr & 7);
      *(uint2*)&sP[w][lr * 64 + blk * 8 + (lg & 1) * 4] = make_uint2(lo32, hi32);
    }

    // O += P V
#pragma unroll
    for (int kk = 0; kk < 2; ++kk) {
      short8 pf = *(const short8*)&sP[w][lr * 64 + (((kk * 4 + lg) ^ (lr & 7))) * 8];
      __builtin_amdgcn_s_setprio(1);
#pragma unroll
      for (int nf = 0; nf < 4; ++nf) {
        int s = ((kk * 4 + lg) ^ (lr & 7));
        short8 vf = *(const short8*)&sV[buf][(nf * 16 + lr) * 64 + s * 8];
        acc[nf] = __builtin_amdgcn_mfma_f32_16x16x32_bf16(pf, vf, acc[nf], 0, 0, 0);
      }
      __builtin_amdgcn_s_setprio(0);
    }

    if (idx + 1 < nkv) __syncthreads();
  }
#undef KVB

  // block-level l reduce: once instead of per-tile
  l_run += __shfl_xor(l_run, 16);
  l_run += __shfl_xor(l_run, 32);

  if (windowed) {
    if (active) {
      float lq[4];
#pragma unroll
      for (int r = 0; r < 4; ++r) lq[r] = __shfl(l_run, lg * 4 + r);
#pragma unroll
      for (int nf = 0; nf < 4; ++nf)
#pragma unroll
        for (int r = 0; r < 4; ++r) {
          float v = acc[nf][r] / lq[r];
          AO[(size_t)(qw + lg * 4 + r) * DMODEL + h * DKH + nf * 16 + lr] = f2bf(v);
        }
    }
  } else if (active) {
    const int pbase = (h * NSPLIT + split) * 64;
#pragma unroll
    for (int nf = 0; nf < 4; ++nf)
#pragma unroll
      for (int r = 0; r < 4; ++r)
        pacc[(size_t)(pbase + wq * 16 + lg * 4 + r) * 64 + nf * 16 + lr] = acc[nf][r];
    if (lane < 16) {
      int bb = (pbase + wq * 16 + lane) * 2;
      pml[bb] = m_run;
      pml[bb + 1] = l_run;
    }
  }
}

// ---------------- merge partials for global q rows (exp2 domain) ----------------
__global__ __launch_bounds__(256)
void merge_kernel(const float* __restrict__ pacc, const float* __restrict__ pml,
                  u16t* __restrict__ AO)
{
  const int h = blockIdx.x;
  const int tid = threadIdx.x;
  const int row = tid >> 2;
  const int d0 = (tid & 3) * 16;

  float M = -1e30f;
#pragma unroll
  for (int s = 0; s < NSPLIT; ++s)
    M = fmaxf(M, pml[((h * NSPLIT + s) * 64 + row) * 2]);

  float L = 0.f;
  float o[16];
#pragma unroll
  for (int e = 0; e < 16; ++e) o[e] = 0.f;

#pragma unroll
  for (int s = 0; s < NSPLIT; ++s) {
    int b = ((h * NSPLIT + s) * 64 + row) * 2;
    float sc = exp2f(pml[b] - M);
    L += pml[b + 1] * sc;
    const float4* a = (const float4*)(pacc + ((size_t)(h * NSPLIT + s) * 64 + row) * 64 + d0);
#pragma unroll
    for (int q4 = 0; q4 < 4; ++q4) {
      float4 av = a[q4];
      o[q4 * 4 + 0] += av.x * sc;
      o[q4 * 4 + 1] += av.y * sc;
      o[q4 * 4 + 2] += av.z * sc;
      o[q4 * 4 + 3] += av.w * sc;
    }
  }
  float inv = 1.f / L;
#pragma unroll
  for (int e = 0; e < 16; ++e)
    AO[(size_t)row * DMODEL + h * DKH + d0 + e] = f2bf(o[e] * inv);
}

// ---------------- launch ----------------
extern "C" void kernel_launch(void* const* d_in, const int* in_sizes, int n_in,
                              void* d_out, int out_size, void* d_ws, size_t ws_size,
                              hipStream_t stream) {
  const float* q   = (const float*)d_in[0];
  const float* k   = (const float*)d_in[1];
  const float* v   = (const float*)d_in[2];
  const float* w_q = (const float*)d_in[3];
  const float* b_q = (const float*)d_in[4];
  const float* w_k = (const float*)d_in[5];
  const float* b_k = (const float*)d_in[6];
  const float* w_v = (const float*)d_in[7];
  const float* b_v = (const float*)d_in[8];
  const float* w_o = (const float*)d_in[9];
  const float* b_o = (const float*)d_in[10];

  u16t* ws = (u16t*)d_ws;
  const size_t SZX = (size_t)S_LEN * DMODEL;   // 2^22
  const size_t SZW = (size_t)DMODEL * DMODEL;  // 2^20
  u16t* xq  = ws;
  u16t* xk  = xq + SZX;
  u16t* xv  = xk + SZX;
  u16t* wb0 = xv + SZX;
  u16t* wb1 = wb0 + SZW;
  u16t* wb2 = wb1 + SZW;
  u16t* wb3 = wb2 + SZW;
  u16t* Qp  = wb3 + SZW;
  u16t* Kp  = Qp + SZX;
  u16t* Vt  = Kp + SZX;   // V^T: [NHEADS*DKH][S_LEN]
  u16t* AO  = xk;         // dead after gemm_qkv
  float* pacc = (float*)xq;
  float* pml  = pacc + (size_t)NHEADS * NSPLIT * 64 * 64;

  dim3 blk(256);

  cvt_all<<<(int)((4 * SZW + 3 * SZX) / 1024), blk, 0, stream>>>(
      w_q, w_k, w_v, w_o, q, k, v, wb0, wb1, wb2, wb3, xq, xk, xv);

  gemm_qkv<<<768, blk, 0, stream>>>(xq, xk, xv, wb0, wb1, wb2, b_q, b_k, b_v, Qp, Kp, Vt);

  attn_kernel<<<(32 + NSPLIT) * NHEADS, dim3(512), 0, stream>>>(Qp, Kp, Vt, AO, pacc, pml);
  merge_kernel<<<NHEADS, blk, 0, stream>>>(pacc, pml, AO);

  gemm_o<<<512, blk, 0, stream>>>(AO, wb3, b_o, (float*)d_out);
}

// Round 21
// 110.036 us; speedup vs baseline: 1.0474x; 1.0474x over previous
//
#include <hip/hip_runtime.h>

#define S_LEN 4096
#define DMODEL 1024
#define NHEADS 16
#define DKH 64
#define WIN 256
#define GTOK 64
#define NSPLIT 8

typedef unsigned short u16t;
typedef __attribute__((ext_vector_type(8))) short short8;
typedef __attribute__((ext_vector_type(4))) float f32x4;

__device__ __forceinline__ u16t f2bf(float x) {
  union { float f; unsigned int u; } v; v.f = x;
  unsigned int r = v.u + 0x7FFFu + ((v.u >> 16) & 1u);
  return (u16t)(r >> 16);
}

__device__ __forceinline__ unsigned int cvtpk(float lo, float hi) {
  unsigned int r;
  asm("v_cvt_pk_bf16_f32 %0, %1, %2" : "=v"(r) : "v"(lo), "v"(hi));
  return r;
}

__device__ __forceinline__ void gload_lds16(const u16t* g, u16t* l) {
  __builtin_amdgcn_global_load_lds(
      (const __attribute__((address_space(1))) void*)g,
      (__attribute__((address_space(3))) void*)l, 16, 0, 0);
}

// ---------------- fused fp32 -> bf16 convert (all 7 tensors, one launch) -------
__global__ void cvt_all(const float* __restrict__ s0, const float* __restrict__ s1,
                        const float* __restrict__ s2, const float* __restrict__ s3,
                        const float* __restrict__ s4, const float* __restrict__ s5,
                        const float* __restrict__ s6,
                        u16t* __restrict__ d0, u16t* __restrict__ d1,
                        u16t* __restrict__ d2, u16t* __restrict__ d3,
                        u16t* __restrict__ d4, u16t* __restrict__ d5,
                        u16t* __restrict__ d6) {
  size_t i = (size_t)blockIdx.x * 1024 + threadIdx.x * 4;
  const float* s; u16t* d; size_t local;
  if (i < ((size_t)4 << 20)) {          // 4 weight matrices, 2^20 each
    int which = (int)(i >> 20);
    local = i & ((1u << 20) - 1);
    s = which == 0 ? s0 : which == 1 ? s1 : which == 2 ? s2 : s3;
    d = which == 0 ? d0 : which == 1 ? d1 : which == 2 ? d2 : d3;
  } else {                              // 3 activations, 2^22 each
    size_t j = i - ((size_t)4 << 20);
    int which = (int)(j >> 22);
    local = j & ((1u << 22) - 1);
    s = which == 0 ? s4 : which == 1 ? s5 : s6;
    d = which == 0 ? d4 : which == 1 ? d5 : d6;
  }
  float4 f = *(const float4*)(s + local);
  unsigned int lo = (unsigned int)f2bf(f.x) | ((unsigned int)f2bf(f.y) << 16);
  unsigned int hi = (unsigned int)f2bf(f.z) | ((unsigned int)f2bf(f.w) << 16);
  *(uint2*)(d + local) = make_uint2(lo, hi);
}

// ---------------- bf16 GEMM body: Y = A @ B^T + bias, * alpha -------------------
// Double-buffered LDS: stage(t+1) issued BEFORE compute(t), one barrier per
// K-step.
#define BN 128
#define GBK 64

template<int OUT_F32, int BMT, int BIAS_ROW>
__device__ __forceinline__
void gemm_body(u16t* __restrict__ smem,
               const u16t* __restrict__ A, const u16t* __restrict__ B,
               const float* __restrict__ bias, void* __restrict__ Y,
               int N, int K, float alpha, int m0, int n0)
{
  constexpr int MF = BMT / 32;
  constexpr int CA_ISS = BMT * 2 / 64;
  constexpr int TILE = (BMT + BN) * GBK;   // u16 per buffer

  const int tid = threadIdx.x;
  const int lane = tid & 63;
  const int lr = lane & 15, lg = lane >> 4;
  const int w = tid >> 6;
  const int wm = (w >> 1) * (MF * 16), wn = (w & 1) * 64;

  f32x4 acc[MF][4] = {};
  const int nk = K / GBK;

  auto stage = [&](int buf, int kt) {
    u16t* sA = smem + buf * TILE;
    u16t* sB = sA + BMT * GBK;
#pragma unroll
    for (int i = 0; i < CA_ISS; ++i) {
      int c0 = w * (BMT * 2) + i * 64;
      int c = c0 + lane;
      int row = c >> 3, g = (c & 7) ^ (row & 7);
      gload_lds16(A + (size_t)(m0 + row) * K + kt * GBK + g * 8, sA + (size_t)c0 * 8);
    }
#pragma unroll
    for (int i = 0; i < 4; ++i) {
      int c0 = w * 256 + i * 64;
      int c = c0 + lane;
      int row = c >> 3, g = (c & 7) ^ (row & 7);
      gload_lds16(B + (size_t)(n0 + row) * K + kt * GBK + g * 8, sB + (size_t)c0 * 8);
    }
  };

  stage(0, 0);
  __syncthreads();

  for (int kt = 0; kt < nk; ++kt) {
    const int buf = kt & 1;
    if (kt + 1 < nk) stage(buf ^ 1, kt + 1);   // overlap with compute below

    const u16t* sA = smem + buf * TILE;
    const u16t* sB = sA + BMT * GBK;

    short8 af[MF][2], bf[4][2];
#pragma unroll
    for (int mf = 0; mf < MF; ++mf)
#pragma unroll
      for (int kk = 0; kk < 2; ++kk) {
        int s = ((kk * 4 + lg) ^ (lr & 7));
        af[mf][kk] = *(const short8*)&sA[(wm + mf * 16 + lr) * GBK + s * 8];
      }
#pragma unroll
    for (int nf = 0; nf < 4; ++nf)
#pragma unroll
      for (int kk = 0; kk < 2; ++kk) {
        int s = ((kk * 4 + lg) ^ (lr & 7));
        bf[nf][kk] = *(const short8*)&sB[(wn + nf * 16 + lr) * GBK + s * 8];
      }
    __builtin_amdgcn_s_setprio(1);
#pragma unroll
    for (int kk = 0; kk < 2; ++kk)
#pragma unroll
      for (int mf = 0; mf < MF; ++mf)
#pragma unroll
        for (int nf = 0; nf < 4; ++nf)
          acc[mf][nf] = __builtin_amdgcn_mfma_f32_16x16x32_bf16(af[mf][kk], bf[nf][kk], acc[mf][nf], 0, 0, 0);
    __builtin_amdgcn_s_setprio(0);

    if (kt + 1 < nk) __syncthreads();  // buf^1 staged; all waves done reading buf
  }

#pragma unroll
  for (int nf = 0; nf < 4; ++nf) {
    int col = n0 + wn + nf * 16 + lr;
    float bvc = BIAS_ROW ? 0.f : bias[col];
#pragma unroll
    for (int mf = 0; mf < MF; ++mf)
#pragma unroll
      for (int r = 0; r < 4; ++r) {
        int row = m0 + wm + mf * 16 + lg * 4 + r;
        float bv = BIAS_ROW ? bias[row] : bvc;
        float v = (acc[mf][nf][r] + bv) * alpha;
        if (OUT_F32) ((float*)Y)[(size_t)row * N + col] = v;
        else         ((u16t*)Y)[(size_t)row * N + col] = f2bf(v);
      }
  }
}

// fused Q/K/V projection: 768 blocks (1D), bijective XCD swizzle (96 blocks/XCD)
#define QSCALE 0.18033688011112042f
__global__ __launch_bounds__(256)
void gemm_qkv(const u16t* __restrict__ xq, const u16t* __restrict__ xk, const u16t* __restrict__ xv,
              const u16t* __restrict__ wq, const u16t* __restrict__ wk, const u16t* __restrict__ wv,
              const float* __restrict__ bq, const float* __restrict__ bk, const float* __restrict__ bv,
              u16t* __restrict__ Qp, u16t* __restrict__ Kp, u16t* __restrict__ Vt)
{
  __shared__ __align__(16) u16t smem[2 * (128 + 128) * GBK];  // 64 KB (2 buffers)

  int b = blockIdx.x;
  int wid = (b & 7) * 96 + (b >> 3);
  int z = wid >> 8;
  int rem = wid & 255;
  if (z == 0) {
    gemm_body<0, 128, 0>(smem, xq, wq, bq, Qp, DMODEL, DMODEL, QSCALE, (rem >> 3) * 128, (rem & 7) * BN);
  } else if (z == 1) {
    gemm_body<0, 128, 0>(smem, xk, wk, bk, Kp, DMODEL, DMODEL, 1.0f, (rem >> 3) * 128, (rem & 7) * BN);
  } else {
    gemm_body<0, 128, 1>(smem, wv, xv, bv, Vt, S_LEN, DMODEL, 1.0f, (rem & 7) * 128, (rem >> 3) * BN);
  }
}

__global__ __launch_bounds__(256)
void gemm_o(const u16t* __restrict__ A, const u16t* __restrict__ B,
            const float* __restrict__ bias, float* __restrict__ Y)
{
  __shared__ __align__(16) u16t smem[2 * (64 + 128) * GBK];  // 48 KB (2 buffers)

  int b = blockIdx.x;
  int wid = (b & 7) * 64 + (b >> 3);
  int my = wid >> 3, mx = wid & 7;
  gemm_body<1, 64, 0>(smem, A, B, bias, Y, DMODEL, DMODEL, 1.0f, my * 64, mx * BN);
}

// ---------------- flash-style sparse attention (swapped QK^T, gload_lds dbuf) ----
// T1 XCD swizzle (K/V L2-resident); LDS staging is load-bearing (r12 lesson);
// 4-wave / 64 q-rows per block (8-wave variant regressed: more tiles/block +
// 512-thread barrier skew + grid imbalance — r19).
// Softmax: per-lane l accumulation + gated max reduce (vote; shfls only on jump).
__global__ __launch_bounds__(256)
void attn_kernel(const u16t* __restrict__ Qp, const u16t* __restrict__ Kp,
                 const u16t* __restrict__ Vt, u16t* __restrict__ AO,
                 float* __restrict__ pacc, float* __restrict__ pml)
{
  // 16 + 16 + 8 = 40 KB exactly -> 4 blocks/CU
  __shared__ __align__(16) u16t sK[2][64 * 64];
  __shared__ __align__(16) u16t sV[2][64 * 64];
  __shared__ __align__(16) u16t sP[4][16 * 64];

  const int b = blockIdx.x;                    // 0..1135
  const int wid = (b & 7) * 142 + (b >> 3);    // XCD-contiguous work id
  const int h = wid / 71;
  const int x = wid % 71;                      // 0..70 within head

  const int tid = threadIdx.x, w = tid >> 6, lane = tid & 63;
  const int lr = lane & 15, lg = lane >> 4;

  const bool windowed = (x < 63);
  const int qb = windowed ? (x + 1) : 0;
  const int split = windowed ? 0 : (x - 63);
  const int qw = qb * 64 + w * 16;

  short8 qf[2];
#pragma unroll
  for (int kk = 0; kk < 2; ++kk)
    qf[kk] = *(const short8*)(Qp + (size_t)(qw + lr) * DMODEL + h * DKH + kk * 32 + lg * 8);

  f32x4 acc[4] = {};
  float m_run = -1e30f;   // group-uniform (per q-row = lr group) by induction
  float l_run = 0.f;      // PER-LANE partial sum; reduced once at epilogue

  int lo = 1, nkv;
  if (windowed) {
    lo = (qb - 4 < 1) ? 1 : qb - 4;
    int hi = (qb + 4 > 63) ? 63 : qb + 4;
    nkv = hi - lo + 2;  // {0} ∪ [lo..hi]
  } else {
    nkv = 64 / NSPLIT;
  }

#define KVB(idx) (windowed ? ((idx) == 0 ? 0 : lo + (idx) - 1) : (split * (64 / NSPLIT) + (idx)))

  auto stage = [&](int buf, int kvb) {
    int kv0 = kvb * 64;
#pragma unroll
    for (int j = 0; j < 2; ++j) {
      int c = tid + j * 256;
      int row = c >> 3, g = (c & 7) ^ (row & 7);
      gload_lds16(Kp + (size_t)(kv0 + row) * DMODEL + h * DKH + g * 8, &sK[buf][c * 8]);
    }
#pragma unroll
    for (int j = 0; j < 2; ++j) {
      int c = tid + j * 256;
      int row = c >> 3, g = (c & 7) ^ (row & 7);
      gload_lds16(Vt + (size_t)(h * DKH + row) * S_LEN + kv0 + g * 8, &sV[buf][c * 8]);
    }
  };

  stage(0, KVB(0));
  __syncthreads();

  for (int idx = 0; idx < nkv; ++idx) {
    const int buf = idx & 1;
    const int kvb = KVB(idx);
    const int kv0 = kvb * 64;

    if (idx + 1 < nkv) stage(buf ^ 1, KVB(idx + 1));

    // S^T = K Q^T: sacc[nf][r] = S[k = kv0 + nf*16 + lg*4 + r][q = qw + lr]
    f32x4 sacc[4] = {};
    __builtin_amdgcn_s_setprio(1);
#pragma unroll
    for (int kk = 0; kk < 2; ++kk)
#pragma unroll
      for (int nf = 0; nf < 4; ++nf) {
        int s = ((kk * 4 + lg) ^ (lr & 7));
        short8 kf = *(const short8*)&sK[buf][(nf * 16 + lr) * 64 + s * 8];
        sacc[nf] = __builtin_amdgcn_mfma_f32_16x16x32_bf16(kf, qf[kk], sacc[nf], 0, 0, 0);
      }
    __builtin_amdgcn_s_setprio(0);

    // mask: only the two edge tiles can mask, and NEVER the global tile kvb==0
    if (windowed && (kvb == qb + 4 || (kvb == qb - 4 && kvb > 0))) {
      int qg = qw + lr;
#pragma unroll
      for (int nf = 0; nf < 4; ++nf)
#pragma unroll
        for (int r = 0; r < 4; ++r) {
          int sg = kv0 + nf * 16 + lg * 4 + r;
          int diff = qg - sg; if (diff < 0) diff = -diff;
          if (diff > WIN) sacc[nf][r] = -1e30f;
        }
    }

    // per-lane local max (no cross-lane) via max3-friendly triples
    float rm0 = fmaxf(fmaxf(sacc[0][0], sacc[0][1]), sacc[0][2]);
    float rm1 = fmaxf(fmaxf(sacc[0][3], sacc[1][0]), sacc[1][1]);
    float rm2 = fmaxf(fmaxf(sacc[1][2], sacc[1][3]), sacc[2][0]);
    float rm3 = fmaxf(fmaxf(sacc[2][1], sacc[2][2]), sacc[2][3]);
    float rm4 = fmaxf(fmaxf(sacc[3][0], sacc[3][1]), sacc[3][2]);
    float rm = fmaxf(fmaxf(rm0, rm1), fmaxf(fmaxf(rm2, rm3), fmaxf(rm4, sacc[3][3])));

    // gated max-reduce + defer-max (T13): cross-lane work only if a lane's
    // local max jumped by > 11 bits (~8 nats) over the running group max.
    if (!__all(rm <= m_run + 11.0f)) {
      rm = fmaxf(rm, __shfl_xor(rm, 16));
      rm = fmaxf(rm, __shfl_xor(rm, 32));
      float mnew = fmaxf(m_run, rm);
      float corr = exp2f(m_run - mnew);
      m_run = mnew;
      l_run *= corr;
      float cq[4];
#pragma unroll
      for (int r = 0; r < 4; ++r) cq[r] = __shfl(corr, lg * 4 + r);
#pragma unroll
      for (int nf = 0; nf < 4; ++nf)
#pragma unroll
        for (int r = 0; r < 4; ++r) acc[nf][r] *= cq[r];
    }

    float p[4][4];
    float rs = 0.f;
#pragma unroll
    for (int nf = 0; nf < 4; ++nf)
#pragma unroll
      for (int r = 0; r < 4; ++r) {
        float e = exp2f(sacc[nf][r] - m_run);
        p[nf][r] = e;
        rs += e;
      }
    l_run += rs;   // per-lane partial; no per-tile shfl reduce

    // P -> LDS via v_cvt_pk_bf16_f32; stride 64 with XOR-block swizzle
#pragma unroll
    for (int nf = 0; nf < 4; ++nf) {
      unsigned int lo32 = cvtpk(p[nf][0], p[nf][1]);
      unsigned int hi32 = cvtpk(p[nf][2], p[nf][3]);
      int blk = (nf * 2 + (lg >> 1)) ^ (lr & 7);
      *(uint2*)&sP[w][lr * 64 + blk * 8 + (lg & 1) * 4] = make_uint2(lo32, hi32);
    }

    // O += P V : pf reads block kk*4+lg (same XOR); vf = V^T row d = nf*16+lr
#pragma unroll
    for (int kk = 0; kk < 2; ++kk) {
      short8 pf = *(const short8*)&sP[w][lr * 64 + (((kk * 4 + lg) ^ (lr & 7))) * 8];
      __builtin_amdgcn_s_setprio(1);
#pragma unroll
      for (int nf = 0; nf < 4; ++nf) {
        int s = ((kk * 4 + lg) ^ (lr & 7));
        short8 vf = *(const short8*)&sV[buf][(nf * 16 + lr) * 64 + s * 8];
        acc[nf] = __builtin_amdgcn_mfma_f32_16x16x32_bf16(pf, vf, acc[nf], 0, 0, 0);
      }
      __builtin_amdgcn_s_setprio(0);
    }

    if (idx + 1 < nkv) __syncthreads();  // drains next-tile gloads + joins waves
  }
#undef KVB

  // block-level l reduce: once instead of per-tile
  l_run += __shfl_xor(l_run, 16);
  l_run += __shfl_xor(l_run, 32);

  if (windowed) {
    float lq[4];
#pragma unroll
    for (int r = 0; r < 4; ++r) lq[r] = __shfl(l_run, lg * 4 + r);
#pragma unroll
    for (int nf = 0; nf < 4; ++nf)
#pragma unroll
      for (int r = 0; r < 4; ++r) {
        float v = acc[nf][r] / lq[r];
        AO[(size_t)(qw + lg * 4 + r) * DMODEL + h * DKH + nf * 16 + lr] = f2bf(v);
      }
  } else {
    const int pbase = (h * NSPLIT + split) * 64;
#pragma unroll
    for (int nf = 0; nf < 4; ++nf)
#pragma unroll
      for (int r = 0; r < 4; ++r)
        pacc[(size_t)(pbase + w * 16 + lg * 4 + r) * 64 + nf * 16 + lr] = acc[nf][r];
    if (lane < 16) {
      int bb = (pbase + w * 16 + lane) * 2;
      pml[bb] = m_run;
      pml[bb + 1] = l_run;
    }
  }
}

// ---------------- merge partials for global q rows (exp2 domain) ----------------
__global__ __launch_bounds__(256)
void merge_kernel(const float* __restrict__ pacc, const float* __restrict__ pml,
                  u16t* __restrict__ AO)
{
  const int h = blockIdx.x;
  const int tid = threadIdx.x;
  const int row = tid >> 2;
  const int d0 = (tid & 3) * 16;

  float M = -1e30f;
#pragma unroll
  for (int s = 0; s < NSPLIT; ++s)
    M = fmaxf(M, pml[((h * NSPLIT + s) * 64 + row) * 2]);

  float L = 0.f;
  float o[16];
#pragma unroll
  for (int e = 0; e < 16; ++e) o[e] = 0.f;

#pragma unroll
  for (int s = 0; s < NSPLIT; ++s) {
    int b = ((h * NSPLIT + s) * 64 + row) * 2;
    float sc = exp2f(pml[b] - M);
    L += pml[b + 1] * sc;
    const float4* a = (const float4*)(pacc + ((size_t)(h * NSPLIT + s) * 64 + row) * 64 + d0);
#pragma unroll
    for (int q4 = 0; q4 < 4; ++q4) {
      float4 av = a[q4];
      o[q4 * 4 + 0] += av.x * sc;
      o[q4 * 4 + 1] += av.y * sc;
      o[q4 * 4 + 2] += av.z * sc;
      o[q4 * 4 + 3] += av.w * sc;
    }
  }
  float inv = 1.f / L;
#pragma unroll
  for (int e = 0; e < 16; ++e)
    AO[(size_t)row * DMODEL + h * DKH + d0 + e] = f2bf(o[e] * inv);
}

// ---------------- launch ----------------
extern "C" void kernel_launch(void* const* d_in, const int* in_sizes, int n_in,
                              void* d_out, int out_size, void* d_ws, size_t ws_size,
                              hipStream_t stream) {
  const float* q   = (const float*)d_in[0];
  const float* k   = (const float*)d_in[1];
  const float* v   = (const float*)d_in[2];
  const float* w_q = (const float*)d_in[3];
  const float* b_q = (const float*)d_in[4];
  const float* w_k = (const float*)d_in[5];
  const float* b_k = (const float*)d_in[6];
  const float* w_v = (const float*)d_in[7];
  const float* b_v = (const float*)d_in[8];
  const float* w_o = (const float*)d_in[9];
  const float* b_o = (const float*)d_in[10];

  u16t* ws = (u16t*)d_ws;
  const size_t SZX = (size_t)S_LEN * DMODEL;   // 2^22
  const size_t SZW = (size_t)DMODEL * DMODEL;  // 2^20
  u16t* xq  = ws;
  u16t* xk  = xq + SZX;
  u16t* xv  = xk + SZX;
  u16t* wb0 = xv + SZX;
  u16t* wb1 = wb0 + SZW;
  u16t* wb2 = wb1 + SZW;
  u16t* wb3 = wb2 + SZW;
  u16t* Qp  = wb3 + SZW;
  u16t* Kp  = Qp + SZX;
  u16t* Vt  = Kp + SZX;   // V^T: [NHEADS*DKH][S_LEN]
  u16t* AO  = xk;         // dead after gemm_qkv
  float* pacc = (float*)xq;
  float* pml  = pacc + (size_t)NHEADS * NSPLIT * 64 * 64;

  dim3 blk(256);

  cvt_all<<<(int)((4 * SZW + 3 * SZX) / 1024), blk, 0, stream>>>(
      w_q, w_k, w_v, w_o, q, k, v, wb0, wb1, wb2, wb3, xq, xk, xv);

  gemm_qkv<<<768, blk, 0, stream>>>(xq, xk, xv, wb0, wb1, wb2, b_q, b_k, b_v, Qp, Kp, Vt);

  attn_kernel<<<(63 + NSPLIT) * NHEADS, blk, 0, stream>>>(Qp, Kp, Vt, AO, pacc, pml);
  merge_kernel<<<NHEADS, blk, 0, stream>>>(pacc, pml, AO);

  gemm_o<<<512, blk, 0, stream>>>(AO, wb3, b_o, (float*)d_out);
}

// Round 22
// 107.134 us; speedup vs baseline: 1.0757x; 1.0271x over previous
//
#include <hip/hip_runtime.h>

#define S_LEN 4096
#define DMODEL 1024
#define NHEADS 16
#define DKH 64
#define WIN 256
#define GTOK 64
#define NSPLIT 8

typedef unsigned short u16t;
typedef __attribute__((ext_vector_type(8))) short short8;
typedef __attribute__((ext_vector_type(4))) float f32x4;

__device__ __forceinline__ u16t f2bf(float x) {
  union { float f; unsigned int u; } v; v.f = x;
  unsigned int r = v.u + 0x7FFFu + ((v.u >> 16) & 1u);
  return (u16t)(r >> 16);
}

__device__ __forceinline__ unsigned int cvtpk(float lo, float hi) {
  unsigned int r;
  asm("v_cvt_pk_bf16_f32 %0, %1, %2" : "=v"(r) : "v"(lo), "v"(hi));
  return r;
}

__device__ __forceinline__ void gload_lds16(const u16t* g, u16t* l) {
  __builtin_amdgcn_global_load_lds(
      (const __attribute__((address_space(1))) void*)g,
      (__attribute__((address_space(3))) void*)l, 16, 0, 0);
}

// ---------------- fused fp32 -> bf16 convert (all 7 tensors, one launch) -------
__global__ void cvt_all(const float* __restrict__ s0, const float* __restrict__ s1,
                        const float* __restrict__ s2, const float* __restrict__ s3,
                        const float* __restrict__ s4, const float* __restrict__ s5,
                        const float* __restrict__ s6,
                        u16t* __restrict__ d0, u16t* __restrict__ d1,
                        u16t* __restrict__ d2, u16t* __restrict__ d3,
                        u16t* __restrict__ d4, u16t* __restrict__ d5,
                        u16t* __restrict__ d6) {
  size_t i = (size_t)blockIdx.x * 1024 + threadIdx.x * 4;
  const float* s; u16t* d; size_t local;
  if (i < ((size_t)4 << 20)) {          // 4 weight matrices, 2^20 each
    int which = (int)(i >> 20);
    local = i & ((1u << 20) - 1);
    s = which == 0 ? s0 : which == 1 ? s1 : which == 2 ? s2 : s3;
    d = which == 0 ? d0 : which == 1 ? d1 : which == 2 ? d2 : d3;
  } else {                              // 3 activations, 2^22 each
    size_t j = i - ((size_t)4 << 20);
    int which = (int)(j >> 22);
    local = j & ((1u << 22) - 1);
    s = which == 0 ? s4 : which == 1 ? s5 : s6;
    d = which == 0 ? d4 : which == 1 ? d5 : d6;
  }
  float4 f = *(const float4*)(s + local);
  unsigned int lo = (unsigned int)f2bf(f.x) | ((unsigned int)f2bf(f.y) << 16);
  unsigned int hi = (unsigned int)f2bf(f.z) | ((unsigned int)f2bf(f.w) << 16);
  *(uint2*)(d + local) = make_uint2(lo, hi);
}

// ---------------- bf16 GEMM body: Y = A @ B^T + bias, * alpha -------------------
// GBKT=64/DBUF=1: double-buffered, stage(t+1) before compute(t) (proven r15).
// GBKT=128/DBUF=0: single 64KB buffer, HALF the K-steps -> half the barrier
// rendezvous (Ω) count; same 2 blocks/CU as the 64KB dbuf, so no occupancy loss
// (the m132 BK=128 regression mechanism is absent).
#define BN 128

template<int OUT_F32, int BMT, int BIAS_ROW, int GBKT, int DBUF>
__device__ __forceinline__
void gemm_body(u16t* __restrict__ smem,
               const u16t* __restrict__ A, const u16t* __restrict__ B,
               const float* __restrict__ bias, void* __restrict__ Y,
               int N, int K, float alpha, int m0, int n0)
{
  constexpr int MF = BMT / 32;
  constexpr int COL8 = GBKT / 8;            // 8-u16 column groups per row
  constexpr int KKN = GBKT / 32;            // K=32 MFMA slices per step
  constexpr int IA = BMT * COL8 / 256;      // A gload issues per thread
  constexpr int IB = BN * COL8 / 256;       // B gload issues per thread
  constexpr int TILE = (BMT + BN) * GBKT;   // u16 per buffer

  const int tid = threadIdx.x;
  const int lane = tid & 63;
  const int lr = lane & 15, lg = lane >> 4;
  const int w = tid >> 6;
  const int wm = (w >> 1) * (MF * 16), wn = (w & 1) * 64;

  f32x4 acc[MF][4] = {};
  const int nk = K / GBKT;

  // LDS slot (row, s) holds global col8 (s ^ (row & (COL8-1))) — rule-21 pair
  auto stage = [&](int buf, int kt) {
    u16t* sA = smem + buf * TILE;
    u16t* sB = sA + BMT * GBKT;
#pragma unroll
    for (int i = 0; i < IA; ++i) {
      int c = i * 256 + tid;
      int row = c / COL8, g = (c % COL8) ^ (row & (COL8 - 1));
      gload_lds16(A + (size_t)(m0 + row) * K + kt * GBKT + g * 8, sA + (size_t)c * 8);
    }
#pragma unroll
    for (int i = 0; i < IB; ++i) {
      int c = i * 256 + tid;
      int row = c / COL8, g = (c % COL8) ^ (row & (COL8 - 1));
      gload_lds16(B + (size_t)(n0 + row) * K + kt * GBKT + g * 8, sB + (size_t)c * 8);
    }
  };

  if (DBUF) { stage(0, 0); __syncthreads(); }

  for (int kt = 0; kt < nk; ++kt) {
    const int buf = DBUF ? (kt & 1) : 0;
    if (DBUF) {
      if (kt + 1 < nk) stage(buf ^ 1, kt + 1);   // overlap with compute below
    } else {
      if (kt) __syncthreads();   // all waves done reading previous step
      stage(0, kt);
      __syncthreads();           // deposits drained
    }

    const u16t* sA = smem + buf * TILE;
    const u16t* sB = sA + BMT * GBKT;

#pragma unroll
    for (int kk = 0; kk < KKN; ++kk) {
      short8 af2[MF], bf2[4];
      int s = ((kk * 4 + lg) ^ (lr & (COL8 - 1)));
#pragma unroll
      for (int mf = 0; mf < MF; ++mf)
        af2[mf] = *(const short8*)&sA[(wm + mf * 16 + lr) * GBKT + s * 8];
#pragma unroll
      for (int nf = 0; nf < 4; ++nf)
        bf2[nf] = *(const short8*)&sB[(wn + nf * 16 + lr) * GBKT + s * 8];
      __builtin_amdgcn_s_setprio(1);
#pragma unroll
      for (int mf = 0; mf < MF; ++mf)
#pragma unroll
        for (int nf = 0; nf < 4; ++nf)
          acc[mf][nf] = __builtin_amdgcn_mfma_f32_16x16x32_bf16(af2[mf], bf2[nf], acc[mf][nf], 0, 0, 0);
      __builtin_amdgcn_s_setprio(0);
    }

    if (DBUF && kt + 1 < nk) __syncthreads();  // buf^1 staged; readers done
  }

#pragma unroll
  for (int nf = 0; nf < 4; ++nf) {
    int col = n0 + wn + nf * 16 + lr;
    float bvc = BIAS_ROW ? 0.f : bias[col];
#pragma unroll
    for (int mf = 0; mf < MF; ++mf)
#pragma unroll
      for (int r = 0; r < 4; ++r) {
        int row = m0 + wm + mf * 16 + lg * 4 + r;
        float bv = BIAS_ROW ? bias[row] : bvc;
        float v = (acc[mf][nf][r] + bv) * alpha;
        if (OUT_F32) ((float*)Y)[(size_t)row * N + col] = v;
        else         ((u16t*)Y)[(size_t)row * N + col] = f2bf(v);
      }
  }
}

// fused Q/K/V projection: 768 blocks (1D), bijective XCD swizzle (96 blocks/XCD)
// BK=128 single-buffer: 8 K-steps (half the barrier count), 64 KB, 2 blocks/CU.
#define QSCALE 0.18033688011112042f
__global__ __launch_bounds__(256)
void gemm_qkv(const u16t* __restrict__ xq, const u16t* __restrict__ xk, const u16t* __restrict__ xv,
              const u16t* __restrict__ wq, const u16t* __restrict__ wk, const u16t* __restrict__ wv,
              const float* __restrict__ bq, const float* __restrict__ bk, const float* __restrict__ bv,
              u16t* __restrict__ Qp, u16t* __restrict__ Kp, u16t* __restrict__ Vt)
{
  __shared__ __align__(16) u16t smem[(128 + 128) * 128];  // 64 KB single buffer

  int b = blockIdx.x;
  int wid = (b & 7) * 96 + (b >> 3);
  int z = wid >> 8;
  int rem = wid & 255;
  if (z == 0) {
    gemm_body<0, 128, 0, 128, 0>(smem, xq, wq, bq, Qp, DMODEL, DMODEL, QSCALE, (rem >> 3) * 128, (rem & 7) * BN);
  } else if (z == 1) {
    gemm_body<0, 128, 0, 128, 0>(smem, xk, wk, bk, Kp, DMODEL, DMODEL, 1.0f, (rem >> 3) * 128, (rem & 7) * BN);
  } else {
    gemm_body<0, 128, 1, 128, 0>(smem, wv, xv, bv, Vt, S_LEN, DMODEL, 1.0f, (rem & 7) * 128, (rem >> 3) * BN);
  }
}

__global__ __launch_bounds__(256)
void gemm_o(const u16t* __restrict__ A, const u16t* __restrict__ B,
            const float* __restrict__ bias, float* __restrict__ Y)
{
  __shared__ __align__(16) u16t smem[2 * (64 + 128) * 64];  // 48 KB (2 buffers)

  int b = blockIdx.x;
  int wid = (b & 7) * 64 + (b >> 3);
  int my = wid >> 3, mx = wid & 7;
  gemm_body<1, 64, 0, 64, 1>(smem, A, B, bias, Y, DMODEL, DMODEL, 1.0f, my * 64, mx * BN);
}

// ---------------- flash-style sparse attention (swapped QK^T, gload_lds dbuf) ----
// T1 XCD swizzle (K/V L2-resident); LDS staging is load-bearing (r12 lesson);
// 4-wave / 64 q-rows per block (8-wave variant regressed — r19).
// Softmax: per-lane l accumulation + gated max reduce (vote; shfls only on jump).
__global__ __launch_bounds__(256)
void attn_kernel(const u16t* __restrict__ Qp, const u16t* __restrict__ Kp,
                 const u16t* __restrict__ Vt, u16t* __restrict__ AO,
                 float* __restrict__ pacc, float* __restrict__ pml)
{
  // 16 + 16 + 8 = 40 KB exactly -> 4 blocks/CU
  __shared__ __align__(16) u16t sK[2][64 * 64];
  __shared__ __align__(16) u16t sV[2][64 * 64];
  __shared__ __align__(16) u16t sP[4][16 * 64];

  const int b = blockIdx.x;                    // 0..1135
  const int wid = (b & 7) * 142 + (b >> 3);    // XCD-contiguous work id
  const int h = wid / 71;
  const int x = wid % 71;                      // 0..70 within head

  const int tid = threadIdx.x, w = tid >> 6, lane = tid & 63;
  const int lr = lane & 15, lg = lane >> 4;

  const bool windowed = (x < 63);
  const int qb = windowed ? (x + 1) : 0;
  const int split = windowed ? 0 : (x - 63);
  const int qw = qb * 64 + w * 16;

  short8 qf[2];
#pragma unroll
  for (int kk = 0; kk < 2; ++kk)
    qf[kk] = *(const short8*)(Qp + (size_t)(qw + lr) * DMODEL + h * DKH + kk * 32 + lg * 8);

  f32x4 acc[4] = {};
  float m_run = -1e30f;   // group-uniform (per q-row = lr group) by induction
  float l_run = 0.f;      // PER-LANE partial sum; reduced once at epilogue

  int lo = 1, nkv;
  if (windowed) {
    lo = (qb - 4 < 1) ? 1 : qb - 4;
    int hi = (qb + 4 > 63) ? 63 : qb + 4;
    nkv = hi - lo + 2;  // {0} ∪ [lo..hi]
  } else {
    nkv = 64 / NSPLIT;
  }

#define KVB(idx) (windowed ? ((idx) == 0 ? 0 : lo + (idx) - 1) : (split * (64 / NSPLIT) + (idx)))

  auto stage = [&](int buf, int kvb) {
    int kv0 = kvb * 64;
#pragma unroll
    for (int j = 0; j < 2; ++j) {
      int c = tid + j * 256;
      int row = c >> 3, g = (c & 7) ^ (row & 7);
      gload_lds16(Kp + (size_t)(kv0 + row) * DMODEL + h * DKH + g * 8, &sK[buf][c * 8]);
    }
#pragma unroll
    for (int j = 0; j < 2; ++j) {
      int c = tid + j * 256;
      int row = c >> 3, g = (c & 7) ^ (row & 7);
      gload_lds16(Vt + (size_t)(h * DKH + row) * S_LEN + kv0 + g * 8, &sV[buf][c * 8]);
    }
  };

  stage(0, KVB(0));
  __syncthreads();

  for (int idx = 0; idx < nkv; ++idx) {
    const int buf = idx & 1;
    const int kvb = KVB(idx);
    const int kv0 = kvb * 64;

    if (idx + 1 < nkv) stage(buf ^ 1, KVB(idx + 1));

    // S^T = K Q^T: sacc[nf][r] = S[k = kv0 + nf*16 + lg*4 + r][q = qw + lr]
    f32x4 sacc[4] = {};
    __builtin_amdgcn_s_setprio(1);
#pragma unroll
    for (int kk = 0; kk < 2; ++kk)
#pragma unroll
      for (int nf = 0; nf < 4; ++nf) {
        int s = ((kk * 4 + lg) ^ (lr & 7));
        short8 kf = *(const short8*)&sK[buf][(nf * 16 + lr) * 64 + s * 8];
        sacc[nf] = __builtin_amdgcn_mfma_f32_16x16x32_bf16(kf, qf[kk], sacc[nf], 0, 0, 0);
      }
    __builtin_amdgcn_s_setprio(0);

    // mask: only the two edge tiles can mask, and NEVER the global tile kvb==0
    if (windowed && (kvb == qb + 4 || (kvb == qb - 4 && kvb > 0))) {
      int qg = qw + lr;
#pragma unroll
      for (int nf = 0; nf < 4; ++nf)
#pragma unroll
        for (int r = 0; r < 4; ++r) {
          int sg = kv0 + nf * 16 + lg * 4 + r;
          int diff = qg - sg; if (diff < 0) diff = -diff;
          if (diff > WIN) sacc[nf][r] = -1e30f;
        }
    }

    // per-lane local max (no cross-lane) via max3-friendly triples
    float rm0 = fmaxf(fmaxf(sacc[0][0], sacc[0][1]), sacc[0][2]);
    float rm1 = fmaxf(fmaxf(sacc[0][3], sacc[1][0]), sacc[1][1]);
    float rm2 = fmaxf(fmaxf(sacc[1][2], sacc[1][3]), sacc[2][0]);
    float rm3 = fmaxf(fmaxf(sacc[2][1], sacc[2][2]), sacc[2][3]);
    float rm4 = fmaxf(fmaxf(sacc[3][0], sacc[3][1]), sacc[3][2]);
    float rm = fmaxf(fmaxf(rm0, rm1), fmaxf(fmaxf(rm2, rm3), fmaxf(rm4, sacc[3][3])));

    // gated max-reduce + defer-max (T13): cross-lane work only if a lane's
    // local max jumped by > 11 bits (~8 nats) over the running group max.
    if (!__all(rm <= m_run + 11.0f)) {
      rm = fmaxf(rm, __shfl_xor(rm, 16));
      rm = fmaxf(rm, __shfl_xor(rm, 32));
      float mnew = fmaxf(m_run, rm);
      float corr = exp2f(m_run - mnew);
      m_run = mnew;
      l_run *= corr;
      float cq[4];
#pragma unroll
      for (int r = 0; r < 4; ++r) cq[r] = __shfl(corr, lg * 4 + r);
#pragma unroll
      for (int nf = 0; nf < 4; ++nf)
#pragma unroll
        for (int r = 0; r < 4; ++r) acc[nf][r] *= cq[r];
    }

    float p[4][4];
    float rs = 0.f;
#pragma unroll
    for (int nf = 0; nf < 4; ++nf)
#pragma unroll
      for (int r = 0; r < 4; ++r) {
        float e = exp2f(sacc[nf][r] - m_run);
        p[nf][r] = e;
        rs += e;
      }
    l_run += rs;   // per-lane partial; no per-tile shfl reduce

    // P -> LDS via v_cvt_pk_bf16_f32; stride 64 with XOR-block swizzle
#pragma unroll
    for (int nf = 0; nf < 4; ++nf) {
      unsigned int lo32 = cvtpk(p[nf][0], p[nf][1]);
      unsigned int hi32 = cvtpk(p[nf][2], p[nf][3]);
      int blk = (nf * 2 + (lg >> 1)) ^ (lr & 7);
      *(uint2*)&sP[w][lr * 64 + blk * 8 + (lg & 1) * 4] = make_uint2(lo32, hi32);
    }

    // O += P V : pf reads block kk*4+lg (same XOR); vf = V^T row d = nf*16+lr
#pragma unroll
    for (int kk = 0; kk < 2; ++kk) {
      short8 pf = *(const short8*)&sP[w][lr * 64 + (((kk * 4 + lg) ^ (lr & 7))) * 8];
      __builtin_amdgcn_s_setprio(1);
#pragma unroll
      for (int nf = 0; nf < 4; ++nf) {
        int s = ((kk * 4 + lg) ^ (lr & 7));
        short8 vf = *(const short8*)&sV[buf][(nf * 16 + lr) * 64 + s * 8];
        acc[nf] = __builtin_amdgcn_mfma_f32_16x16x32_bf16(pf, vf, acc[nf], 0, 0, 0);
      }
      __builtin_amdgcn_s_setprio(0);
    }

    if (idx + 1 < nkv) __syncthreads();  // drains next-tile gloads + joins waves
  }
#undef KVB

  // block-level l reduce: once instead of per-tile
  l_run += __shfl_xor(l_run, 16);
  l_run += __shfl_xor(l_run, 32);

  if (windowed) {
    float lq[4];
#pragma unroll
    for (int r = 0; r < 4; ++r) lq[r] = __shfl(l_run, lg * 4 + r);
#pragma unroll
    for (int nf = 0; nf < 4; ++nf)
#pragma unroll
      for (int r = 0; r < 4; ++r) {
        float v = acc[nf][r] / lq[r];
        AO[(size_t)(qw + lg * 4 + r) * DMODEL + h * DKH + nf * 16 + lr] = f2bf(v);
      }
  } else {
    const int pbase = (h * NSPLIT + split) * 64;
#pragma unroll
    for (int nf = 0; nf < 4; ++nf)
#pragma unroll
      for (int r = 0; r < 4; ++r)
        pacc[(size_t)(pbase + w * 16 + lg * 4 + r) * 64 + nf * 16 + lr] = acc[nf][r];
    if (lane < 16) {
      int bb = (pbase + w * 16 + lane) * 2;
      pml[bb] = m_run;
      pml[bb + 1] = l_run;
    }
  }
}

// ---------------- merge partials for global q rows (exp2 domain) ----------------
__global__ __launch_bounds__(256)
void merge_kernel(const float* __restrict__ pacc, const float* __restrict__ pml,
                  u16t* __restrict__ AO)
{
  const int h = blockIdx.x;
  const int tid = threadIdx.x;
  const int row = tid >> 2;
  const int d0 = (tid & 3) * 16;

  float M = -1e30f;
#pragma unroll
  for (int s = 0; s < NSPLIT; ++s)
    M = fmaxf(M, pml[((h * NSPLIT + s) * 64 + row) * 2]);

  float L = 0.f;
  float o[16];
#pragma unroll
  for (int e = 0; e < 16; ++e) o[e] = 0.f;

#pragma unroll
  for (int s = 0; s < NSPLIT; ++s) {
    int b = ((h * NSPLIT + s) * 64 + row) * 2;
    float sc = exp2f(pml[b] - M);
    L += pml[b + 1] * sc;
    const float4* a = (const float4*)(pacc + ((size_t)(h * NSPLIT + s) * 64 + row) * 64 + d0);
#pragma unroll
    for (int q4 = 0; q4 < 4; ++q4) {
      float4 av = a[q4];
      o[q4 * 4 + 0] += av.x * sc;
      o[q4 * 4 + 1] += av.y * sc;
      o[q4 * 4 + 2] += av.z * sc;
      o[q4 * 4 + 3] += av.w * sc;
    }
  }
  float inv = 1.f / L;
#pragma unroll
  for (int e = 0; e < 16; ++e)
    AO[(size_t)row * DMODEL + h * DKH + d0 + e] = f2bf(o[e] * inv);
}

// ---------------- launch ----------------
extern "C" void kernel_launch(void* const* d_in, const int* in_sizes, int n_in,
                              void* d_out, int out_size, void* d_ws, size_t ws_size,
                              hipStream_t stream) {
  const float* q   = (const float*)d_in[0];
  const float* k   = (const float*)d_in[1];
  const float* v   = (const float*)d_in[2];
  const float* w_q = (const float*)d_in[3];
  const float* b_q = (const float*)d_in[4];
  const float* w_k = (const float*)d_in[5];
  const float* b_k = (const float*)d_in[6];
  const float* w_v = (const float*)d_in[7];
  const float* b_v = (const float*)d_in[8];
  const float* w_o = (const float*)d_in[9];
  const float* b_o = (const float*)d_in[10];

  u16t* ws = (u16t*)d_ws;
  const size_t SZX = (size_t)S_LEN * DMODEL;   // 2^22
  const size_t SZW = (size_t)DMODEL * DMODEL;  // 2^20
  u16t* xq  = ws;
  u16t* xk  = xq + SZX;
  u16t* xv  = xk + SZX;
  u16t* wb0 = xv + SZX;
  u16t* wb1 = wb0 + SZW;
  u16t* wb2 = wb1 + SZW;
  u16t* wb3 = wb2 + SZW;
  u16t* Qp  = wb3 + SZW;
  u16t* Kp  = Qp + SZX;
  u16t* Vt  = Kp + SZX;   // V^T: [NHEADS*DKH][S_LEN]
  u16t* AO  = xk;         // dead after gemm_qkv
  float* pacc = (float*)xq;
  float* pml  = pacc + (size_t)NHEADS * NSPLIT * 64 * 64;

  dim3 blk(256);

  cvt_all<<<(int)((4 * SZW + 3 * SZX) / 1024), blk, 0, stream>>>(
      w_q, w_k, w_v, w_o, q, k, v, wb0, wb1, wb2, wb3, xq, xk, xv);

  gemm_qkv<<<768, blk, 0, stream>>>(xq, xk, xv, wb0, wb1, wb2, b_q, b_k, b_v, Qp, Kp, Vt);

  attn_kernel<<<(63 + NSPLIT) * NHEADS, blk, 0, stream>>>(Qp, Kp, Vt, AO, pacc, pml);
  merge_kernel<<<NHEADS, blk, 0, stream>>>(pacc, pml, AO);

  gemm_o<<<512, blk, 0, stream>>>(AO, wb3, b_o, (float*)d_out);
}

// Round 23
// 106.408 us; speedup vs baseline: 1.0831x; 1.0068x over previous
//
#include <hip/hip_runtime.h>

#define S_LEN 4096
#define DMODEL 1024
#define NHEADS 16
#define DKH 64
#define WIN 256
#define GTOK 64
#define NSPLIT 8

typedef unsigned short u16t;
typedef __attribute__((ext_vector_type(8))) short short8;
typedef __attribute__((ext_vector_type(4))) float f32x4;

__device__ __forceinline__ u16t f2bf(float x) {
  union { float f; unsigned int u; } v; v.f = x;
  unsigned int r = v.u + 0x7FFFu + ((v.u >> 16) & 1u);
  return (u16t)(r >> 16);
}

__device__ __forceinline__ unsigned int cvtpk(float lo, float hi) {
  unsigned int r;
  asm("v_cvt_pk_bf16_f32 %0, %1, %2" : "=v"(r) : "v"(lo), "v"(hi));
  return r;
}

__device__ __forceinline__ void gload_lds16(const u16t* g, u16t* l) {
  __builtin_amdgcn_global_load_lds(
      (const __attribute__((address_space(1))) void*)g,
      (__attribute__((address_space(3))) void*)l, 16, 0, 0);
}

// ---------------- fused fp32 -> bf16 convert (all 7 tensors, one launch) -------
__global__ void cvt_all(const float* __restrict__ s0, const float* __restrict__ s1,
                        const float* __restrict__ s2, const float* __restrict__ s3,
                        const float* __restrict__ s4, const float* __restrict__ s5,
                        const float* __restrict__ s6,
                        u16t* __restrict__ d0, u16t* __restrict__ d1,
                        u16t* __restrict__ d2, u16t* __restrict__ d3,
                        u16t* __restrict__ d4, u16t* __restrict__ d5,
                        u16t* __restrict__ d6) {
  size_t i = (size_t)blockIdx.x * 1024 + threadIdx.x * 4;
  const float* s; u16t* d; size_t local;
  if (i < ((size_t)4 << 20)) {          // 4 weight matrices, 2^20 each
    int which = (int)(i >> 20);
    local = i & ((1u << 20) - 1);
    s = which == 0 ? s0 : which == 1 ? s1 : which == 2 ? s2 : s3;
    d = which == 0 ? d0 : which == 1 ? d1 : which == 2 ? d2 : d3;
  } else {                              // 3 activations, 2^22 each
    size_t j = i - ((size_t)4 << 20);
    int which = (int)(j >> 22);
    local = j & ((1u << 22) - 1);
    s = which == 0 ? s4 : which == 1 ? s5 : s6;
    d = which == 0 ? d4 : which == 1 ? d5 : d6;
  }
  float4 f = *(const float4*)(s + local);
  unsigned int lo = (unsigned int)f2bf(f.x) | ((unsigned int)f2bf(f.y) << 16);
  unsigned int hi = (unsigned int)f2bf(f.z) | ((unsigned int)f2bf(f.w) << 16);
  *(uint2*)(d + local) = make_uint2(lo, hi);
}

// ---------------- bf16 GEMM body: Y = A @ B^T + bias, * alpha -------------------
// GBKT=64/DBUF=1: double-buffered, stage(t+1) before compute(t) (proven r15).
// GBKT=128/DBUF=0: single buffer, HALF the K-steps -> half the barrier
// rendezvous (Ω) count at equal LDS/occupancy (confirmed r22: qkv −3 µs).
#define BN 128

template<int OUT_F32, int BMT, int BIAS_ROW, int GBKT, int DBUF>
__device__ __forceinline__
void gemm_body(u16t* __restrict__ smem,
               const u16t* __restrict__ A, const u16t* __restrict__ B,
               const float* __restrict__ bias, void* __restrict__ Y,
               int N, int K, float alpha, int m0, int n0)
{
  constexpr int MF = BMT / 32;
  constexpr int COL8 = GBKT / 8;            // 8-u16 column groups per row
  constexpr int KKN = GBKT / 32;            // K=32 MFMA slices per step
  constexpr int IA = BMT * COL8 / 256;      // A gload issues per thread
  constexpr int IB = BN * COL8 / 256;       // B gload issues per thread
  constexpr int TILE = (BMT + BN) * GBKT;   // u16 per buffer

  const int tid = threadIdx.x;
  const int lane = tid & 63;
  const int lr = lane & 15, lg = lane >> 4;
  const int w = tid >> 6;
  const int wm = (w >> 1) * (MF * 16), wn = (w & 1) * 64;

  f32x4 acc[MF][4] = {};
  const int nk = K / GBKT;

  // LDS slot (row, s) holds global col8 (s ^ (row & (COL8-1))) — rule-21 pair
  auto stage = [&](int buf, int kt) {
    u16t* sA = smem + buf * TILE;
    u16t* sB = sA + BMT * GBKT;
#pragma unroll
    for (int i = 0; i < IA; ++i) {
      int c = i * 256 + tid;
      int row = c / COL8, g = (c % COL8) ^ (row & (COL8 - 1));
      gload_lds16(A + (size_t)(m0 + row) * K + kt * GBKT + g * 8, sA + (size_t)c * 8);
    }
#pragma unroll
    for (int i = 0; i < IB; ++i) {
      int c = i * 256 + tid;
      int row = c / COL8, g = (c % COL8) ^ (row & (COL8 - 1));
      gload_lds16(B + (size_t)(n0 + row) * K + kt * GBKT + g * 8, sB + (size_t)c * 8);
    }
  };

  if (DBUF) { stage(0, 0); __syncthreads(); }

  for (int kt = 0; kt < nk; ++kt) {
    const int buf = DBUF ? (kt & 1) : 0;
    if (DBUF) {
      if (kt + 1 < nk) stage(buf ^ 1, kt + 1);   // overlap with compute below
    } else {
      if (kt) __syncthreads();   // all waves done reading previous step
      stage(0, kt);
      __syncthreads();           // deposits drained
    }

    const u16t* sA = smem + buf * TILE;
    const u16t* sB = sA + BMT * GBKT;

#pragma unroll
    for (int kk = 0; kk < KKN; ++kk) {
      short8 af2[MF], bf2[4];
      int s = ((kk * 4 + lg) ^ (lr & (COL8 - 1)));
#pragma unroll
      for (int mf = 0; mf < MF; ++mf)
        af2[mf] = *(const short8*)&sA[(wm + mf * 16 + lr) * GBKT + s * 8];
#pragma unroll
      for (int nf = 0; nf < 4; ++nf)
        bf2[nf] = *(const short8*)&sB[(wn + nf * 16 + lr) * GBKT + s * 8];
      __builtin_amdgcn_s_setprio(1);
#pragma unroll
      for (int mf = 0; mf < MF; ++mf)
#pragma unroll
        for (int nf = 0; nf < 4; ++nf)
          acc[mf][nf] = __builtin_amdgcn_mfma_f32_16x16x32_bf16(af2[mf], bf2[nf], acc[mf][nf], 0, 0, 0);
      __builtin_amdgcn_s_setprio(0);
    }

    if (DBUF && kt + 1 < nk) __syncthreads();  // buf^1 staged; readers done
  }

#pragma unroll
  for (int nf = 0; nf < 4; ++nf) {
    int col = n0 + wn + nf * 16 + lr;
    float bvc = BIAS_ROW ? 0.f : bias[col];
#pragma unroll
    for (int mf = 0; mf < MF; ++mf)
#pragma unroll
      for (int r = 0; r < 4; ++r) {
        int row = m0 + wm + mf * 16 + lg * 4 + r;
        float bv = BIAS_ROW ? bias[row] : bvc;
        float v = (acc[mf][nf][r] + bv) * alpha;
        if (OUT_F32) ((float*)Y)[(size_t)row * N + col] = v;
        else         ((u16t*)Y)[(size_t)row * N + col] = f2bf(v);
      }
  }
}

// fused Q/K/V projection: 768 blocks (1D), bijective XCD swizzle (96 blocks/XCD)
// BK=128 single-buffer: 8 K-steps (half the barrier count), 64 KB, 2 blocks/CU.
#define QSCALE 0.18033688011112042f
__global__ __launch_bounds__(256)
void gemm_qkv(const u16t* __restrict__ xq, const u16t* __restrict__ xk, const u16t* __restrict__ xv,
              const u16t* __restrict__ wq, const u16t* __restrict__ wk, const u16t* __restrict__ wv,
              const float* __restrict__ bq, const float* __restrict__ bk, const float* __restrict__ bv,
              u16t* __restrict__ Qp, u16t* __restrict__ Kp, u16t* __restrict__ Vt)
{
  __shared__ __align__(16) u16t smem[(128 + 128) * 128];  // 64 KB single buffer

  int b = blockIdx.x;
  int wid = (b & 7) * 96 + (b >> 3);
  int z = wid >> 8;
  int rem = wid & 255;
  if (z == 0) {
    gemm_body<0, 128, 0, 128, 0>(smem, xq, wq, bq, Qp, DMODEL, DMODEL, QSCALE, (rem >> 3) * 128, (rem & 7) * BN);
  } else if (z == 1) {
    gemm_body<0, 128, 0, 128, 0>(smem, xk, wk, bk, Kp, DMODEL, DMODEL, 1.0f, (rem >> 3) * 128, (rem & 7) * BN);
  } else {
    gemm_body<0, 128, 1, 128, 0>(smem, wv, xv, bv, Vt, S_LEN, DMODEL, 1.0f, (rem & 7) * 128, (rem >> 3) * BN);
  }
}

// o-projection: BK=128 single-buffer too (r22 mechanism): 48 KB, 3 blocks/CU,
// 8 K-steps instead of 16.
__global__ __launch_bounds__(256)
void gemm_o(const u16t* __restrict__ A, const u16t* __restrict__ B,
            const float* __restrict__ bias, float* __restrict__ Y)
{
  __shared__ __align__(16) u16t smem[(64 + 128) * 128];  // 48 KB single buffer

  int b = blockIdx.x;
  int wid = (b & 7) * 64 + (b >> 3);
  int my = wid >> 3, mx = wid & 7;
  gemm_body<1, 64, 0, 128, 0>(smem, A, B, bias, Y, DMODEL, DMODEL, 1.0f, my * 64, mx * BN);
}

// ---------------- flash-style sparse attention (swapped QK^T, gload_lds dbuf) ----
// T1 XCD swizzle (K/V L2-resident); LDS staging is load-bearing (r12 lesson);
// 4-wave / 64 q-rows per block (8-wave variant regressed — r19).
// Softmax: per-lane l accumulation + gated max reduce (vote; shfls only on jump).
__global__ __launch_bounds__(256)
void attn_kernel(const u16t* __restrict__ Qp, const u16t* __restrict__ Kp,
                 const u16t* __restrict__ Vt, u16t* __restrict__ AO,
                 float* __restrict__ pacc, float* __restrict__ pml)
{
  // 16 + 16 + 8 = 40 KB exactly -> 4 blocks/CU
  __shared__ __align__(16) u16t sK[2][64 * 64];
  __shared__ __align__(16) u16t sV[2][64 * 64];
  __shared__ __align__(16) u16t sP[4][16 * 64];

  const int b = blockIdx.x;                    // 0..1135
  const int wid = (b & 7) * 142 + (b >> 3);    // XCD-contiguous work id
  const int h = wid / 71;
  const int x = wid % 71;                      // 0..70 within head

  const int tid = threadIdx.x, w = tid >> 6, lane = tid & 63;
  const int lr = lane & 15, lg = lane >> 4;

  const bool windowed = (x < 63);
  const int qb = windowed ? (x + 1) : 0;
  const int split = windowed ? 0 : (x - 63);
  const int qw = qb * 64 + w * 16;

  short8 qf[2];
#pragma unroll
  for (int kk = 0; kk < 2; ++kk)
    qf[kk] = *(const short8*)(Qp + (size_t)(qw + lr) * DMODEL + h * DKH + kk * 32 + lg * 8);

  f32x4 acc[4] = {};
  float m_run = -1e30f;   // group-uniform (per q-row = lr group) by induction
  float l_run = 0.f;      // PER-LANE partial sum; reduced once at epilogue

  int lo = 1, nkv;
  if (windowed) {
    lo = (qb - 4 < 1) ? 1 : qb - 4;
    int hi = (qb + 4 > 63) ? 63 : qb + 4;
    nkv = hi - lo + 2;  // {0} ∪ [lo..hi]
  } else {
    nkv = 64 / NSPLIT;
  }

#define KVB(idx) (windowed ? ((idx) == 0 ? 0 : lo + (idx) - 1) : (split * (64 / NSPLIT) + (idx)))

  auto stage = [&](int buf, int kvb) {
    int kv0 = kvb * 64;
#pragma unroll
    for (int j = 0; j < 2; ++j) {
      int c = tid + j * 256;
      int row = c >> 3, g = (c & 7) ^ (row & 7);
      gload_lds16(Kp + (size_t)(kv0 + row) * DMODEL + h * DKH + g * 8, &sK[buf][c * 8]);
    }
#pragma unroll
    for (int j = 0; j < 2; ++j) {
      int c = tid + j * 256;
      int row = c >> 3, g = (c & 7) ^ (row & 7);
      gload_lds16(Vt + (size_t)(h * DKH + row) * S_LEN + kv0 + g * 8, &sV[buf][c * 8]);
    }
  };

  stage(0, KVB(0));
  __syncthreads();

  for (int idx = 0; idx < nkv; ++idx) {
    const int buf = idx & 1;
    const int kvb = KVB(idx);
    const int kv0 = kvb * 64;

    if (idx + 1 < nkv) stage(buf ^ 1, KVB(idx + 1));

    // S^T = K Q^T: sacc[nf][r] = S[k = kv0 + nf*16 + lg*4 + r][q = qw + lr]
    f32x4 sacc[4] = {};
    __builtin_amdgcn_s_setprio(1);
#pragma unroll
    for (int kk = 0; kk < 2; ++kk)
#pragma unroll
      for (int nf = 0; nf < 4; ++nf) {
        int s = ((kk * 4 + lg) ^ (lr & 7));
        short8 kf = *(const short8*)&sK[buf][(nf * 16 + lr) * 64 + s * 8];
        sacc[nf] = __builtin_amdgcn_mfma_f32_16x16x32_bf16(kf, qf[kk], sacc[nf], 0, 0, 0);
      }
    __builtin_amdgcn_s_setprio(0);

    // mask: only the two edge tiles can mask, and NEVER the global tile kvb==0
    if (windowed && (kvb == qb + 4 || (kvb == qb - 4 && kvb > 0))) {
      int qg = qw + lr;
#pragma unroll
      for (int nf = 0; nf < 4; ++nf)
#pragma unroll
        for (int r = 0; r < 4; ++r) {
          int sg = kv0 + nf * 16 + lg * 4 + r;
          int diff = qg - sg; if (diff < 0) diff = -diff;
          if (diff > WIN) sacc[nf][r] = -1e30f;
        }
    }

    // per-lane local max (no cross-lane) via max3-friendly triples
    float rm0 = fmaxf(fmaxf(sacc[0][0], sacc[0][1]), sacc[0][2]);
    float rm1 = fmaxf(fmaxf(sacc[0][3], sacc[1][0]), sacc[1][1]);
    float rm2 = fmaxf(fmaxf(sacc[1][2], sacc[1][3]), sacc[2][0]);
    float rm3 = fmaxf(fmaxf(sacc[2][1], sacc[2][2]), sacc[2][3]);
    float rm4 = fmaxf(fmaxf(sacc[3][0], sacc[3][1]), sacc[3][2]);
    float rm = fmaxf(fmaxf(rm0, rm1), fmaxf(fmaxf(rm2, rm3), fmaxf(rm4, sacc[3][3])));

    // gated max-reduce + defer-max (T13): cross-lane work only if a lane's
    // local max jumped by > 11 bits (~8 nats) over the running group max.
    if (!__all(rm <= m_run + 11.0f)) {
      rm = fmaxf(rm, __shfl_xor(rm, 16));
      rm = fmaxf(rm, __shfl_xor(rm, 32));
      float mnew = fmaxf(m_run, rm);
      float corr = exp2f(m_run - mnew);
      m_run = mnew;
      l_run *= corr;
      float cq[4];
#pragma unroll
      for (int r = 0; r < 4; ++r) cq[r] = __shfl(corr, lg * 4 + r);
#pragma unroll
      for (int nf = 0; nf < 4; ++nf)
#pragma unroll
        for (int r = 0; r < 4; ++r) acc[nf][r] *= cq[r];
    }

    float p[4][4];
    float rs = 0.f;
#pragma unroll
    for (int nf = 0; nf < 4; ++nf)
#pragma unroll
      for (int r = 0; r < 4; ++r) {
        float e = exp2f(sacc[nf][r] - m_run);
        p[nf][r] = e;
        rs += e;
      }
    l_run += rs;   // per-lane partial; no per-tile shfl reduce

    // P -> LDS via v_cvt_pk_bf16_f32; stride 64 with XOR-block swizzle
#pragma unroll
    for (int nf = 0; nf < 4; ++nf) {
      unsigned int lo32 = cvtpk(p[nf][0], p[nf][1]);
      unsigned int hi32 = cvtpk(p[nf][2], p[nf][3]);
      int blk = (nf * 2 + (lg >> 1)) ^ (lr & 7);
      *(uint2*)&sP[w][lr * 64 + blk * 8 + (lg & 1) * 4] = make_uint2(lo32, hi32);
    }

    // O += P V : pf reads block kk*4+lg (same XOR); vf = V^T row d = nf*16+lr
#pragma unroll
    for (int kk = 0; kk < 2; ++kk) {
      short8 pf = *(const short8*)&sP[w][lr * 64 + (((kk * 4 + lg) ^ (lr & 7))) * 8];
      __builtin_amdgcn_s_setprio(1);
#pragma unroll
      for (int nf = 0; nf < 4; ++nf) {
        int s = ((kk * 4 + lg) ^ (lr & 7));
        short8 vf = *(const short8*)&sV[buf][(nf * 16 + lr) * 64 + s * 8];
        acc[nf] = __builtin_amdgcn_mfma_f32_16x16x32_bf16(pf, vf, acc[nf], 0, 0, 0);
      }
      __builtin_amdgcn_s_setprio(0);
    }

    if (idx + 1 < nkv) __syncthreads();  // drains next-tile gloads + joins waves
  }
#undef KVB

  // block-level l reduce: once instead of per-tile
  l_run += __shfl_xor(l_run, 16);
  l_run += __shfl_xor(l_run, 32);

  if (windowed) {
    float lq[4];
#pragma unroll
    for (int r = 0; r < 4; ++r) lq[r] = __shfl(l_run, lg * 4 + r);
#pragma unroll
    for (int nf = 0; nf < 4; ++nf)
#pragma unroll
      for (int r = 0; r < 4; ++r) {
        float v = acc[nf][r] / lq[r];
        AO[(size_t)(qw + lg * 4 + r) * DMODEL + h * DKH + nf * 16 + lr] = f2bf(v);
      }
  } else {
    const int pbase = (h * NSPLIT + split) * 64;
#pragma unroll
    for (int nf = 0; nf < 4; ++nf)
#pragma unroll
      for (int r = 0; r < 4; ++r)
        pacc[(size_t)(pbase + w * 16 + lg * 4 + r) * 64 + nf * 16 + lr] = acc[nf][r];
    if (lane < 16) {
      int bb = (pbase + w * 16 + lane) * 2;
      pml[bb] = m_run;
      pml[bb + 1] = l_run;
    }
  }
}

// ---------------- merge partials for global q rows (exp2 domain) ----------------
__global__ __launch_bounds__(256)
void merge_kernel(const float* __restrict__ pacc, const float* __restrict__ pml,
                  u16t* __restrict__ AO)
{
  const int h = blockIdx.x;
  const int tid = threadIdx.x;
  const int row = tid >> 2;
  const int d0 = (tid & 3) * 16;

  float M = -1e30f;
#pragma unroll
  for (int s = 0; s < NSPLIT; ++s)
    M = fmaxf(M, pml[((h * NSPLIT + s) * 64 + row) * 2]);

  float L = 0.f;
  float o[16];
#pragma unroll
  for (int e = 0; e < 16; ++e) o[e] = 0.f;

#pragma unroll
  for (int s = 0; s < NSPLIT; ++s) {
    int b = ((h * NSPLIT + s) * 64 + row) * 2;
    float sc = exp2f(pml[b] - M);
    L += pml[b + 1] * sc;
    const float4* a = (const float4*)(pacc + ((size_t)(h * NSPLIT + s) * 64 + row) * 64 + d0);
#pragma unroll
    for (int q4 = 0; q4 < 4; ++q4) {
      float4 av = a[q4];
      o[q4 * 4 + 0] += av.x * sc;
      o[q4 * 4 + 1] += av.y * sc;
      o[q4 * 4 + 2] += av.z * sc;
      o[q4 * 4 + 3] += av.w * sc;
    }
  }
  float inv = 1.f / L;
#pragma unroll
  for (int e = 0; e < 16; ++e)
    AO[(size_t)row * DMODEL + h * DKH + d0 + e] = f2bf(o[e] * inv);
}

// ---------------- launch ----------------
extern "C" void kernel_launch(void* const* d_in, const int* in_sizes, int n_in,
                              void* d_out, int out_size, void* d_ws, size_t ws_size,
                              hipStream_t stream) {
  const float* q   = (const float*)d_in[0];
  const float* k   = (const float*)d_in[1];
  const float* v   = (const float*)d_in[2];
  const float* w_q = (const float*)d_in[3];
  const float* b_q = (const float*)d_in[4];
  const float* w_k = (const float*)d_in[5];
  const float* b_k = (const float*)d_in[6];
  const float* w_v = (const float*)d_in[7];
  const float* b_v = (const float*)d_in[8];
  const float* w_o = (const float*)d_in[9];
  const float* b_o = (const float*)d_in[10];

  u16t* ws = (u16t*)d_ws;
  const size_t SZX = (size_t)S_LEN * DMODEL;   // 2^22
  const size_t SZW = (size_t)DMODEL * DMODEL;  // 2^20
  u16t* xq  = ws;
  u16t* xk  = xq + SZX;
  u16t* xv  = xk + SZX;
  u16t* wb0 = xv + SZX;
  u16t* wb1 = wb0 + SZW;
  u16t* wb2 = wb1 + SZW;
  u16t* wb3 = wb2 + SZW;
  u16t* Qp  = wb3 + SZW;
  u16t* Kp  = Qp + SZX;
  u16t* Vt  = Kp + SZX;   // V^T: [NHEADS*DKH][S_LEN]
  u16t* AO  = xk;         // dead after gemm_qkv
  float* pacc = (float*)xq;
  float* pml  = pacc + (size_t)NHEADS * NSPLIT * 64 * 64;

  dim3 blk(256);

  cvt_all<<<(int)((4 * SZW + 3 * SZX) / 1024), blk, 0, stream>>>(
      w_q, w_k, w_v, w_o, q, k, v, wb0, wb1, wb2, wb3, xq, xk, xv);

  gemm_qkv<<<768, blk, 0, stream>>>(xq, xk, xv, wb0, wb1, wb2, b_q, b_k, b_v, Qp, Kp, Vt);

  attn_kernel<<<(63 + NSPLIT) * NHEADS, blk, 0, stream>>>(Qp, Kp, Vt, AO, pacc, pml);
  merge_kernel<<<NHEADS, blk, 0, stream>>>(pacc, pml, AO);

  gemm_o<<<512, blk, 0, stream>>>(AO, wb3, b_o, (float*)d_out);
}

// Round 24
// 104.454 us; speedup vs baseline: 1.1033x; 1.0187x over previous
//
#include <hip/hip_runtime.h>

#define S_LEN 4096
#define DMODEL 1024
#define NHEADS 16
#define DKH 64
#define WIN 256
#define GTOK 64
#define NSPLIT 8

typedef unsigned short u16t;
typedef __attribute__((ext_vector_type(8))) short short8;
typedef __attribute__((ext_vector_type(4))) float f32x4;

__device__ __forceinline__ u16t f2bf(float x) {
  union { float f; unsigned int u; } v; v.f = x;
  unsigned int r = v.u + 0x7FFFu + ((v.u >> 16) & 1u);
  return (u16t)(r >> 16);
}

__device__ __forceinline__ unsigned int cvtpk(float lo, float hi) {
  unsigned int r;
  asm("v_cvt_pk_bf16_f32 %0, %1, %2" : "=v"(r) : "v"(lo), "v"(hi));
  return r;
}

__device__ __forceinline__ void gload_lds16(const u16t* g, u16t* l) {
  __builtin_amdgcn_global_load_lds(
      (const __attribute__((address_space(1))) void*)g,
      (__attribute__((address_space(3))) void*)l, 16, 0, 0);
}

// ---------------- fused fp32 -> bf16 convert (all 7 tensors, one launch) -------
__global__ void cvt_all(const float* __restrict__ s0, const float* __restrict__ s1,
                        const float* __restrict__ s2, const float* __restrict__ s3,
                        const float* __restrict__ s4, const float* __restrict__ s5,
                        const float* __restrict__ s6,
                        u16t* __restrict__ d0, u16t* __restrict__ d1,
                        u16t* __restrict__ d2, u16t* __restrict__ d3,
                        u16t* __restrict__ d4, u16t* __restrict__ d5,
                        u16t* __restrict__ d6) {
  size_t i = (size_t)blockIdx.x * 1024 + threadIdx.x * 4;
  const float* s; u16t* d; size_t local;
  if (i < ((size_t)4 << 20)) {          // 4 weight matrices, 2^20 each
    int which = (int)(i >> 20);
    local = i & ((1u << 20) - 1);
    s = which == 0 ? s0 : which == 1 ? s1 : which == 2 ? s2 : s3;
    d = which == 0 ? d0 : which == 1 ? d1 : which == 2 ? d2 : d3;
  } else {                              // 3 activations, 2^22 each
    size_t j = i - ((size_t)4 << 20);
    int which = (int)(j >> 22);
    local = j & ((1u << 22) - 1);
    s = which == 0 ? s4 : which == 1 ? s5 : s6;
    d = which == 0 ? d4 : which == 1 ? d5 : d6;
  }
  float4 f = *(const float4*)(s + local);
  unsigned int lo = (unsigned int)f2bf(f.x) | ((unsigned int)f2bf(f.y) << 16);
  unsigned int hi = (unsigned int)f2bf(f.z) | ((unsigned int)f2bf(f.w) << 16);
  *(uint2*)(d + local) = make_uint2(lo, hi);
}

// ---------------- bf16 GEMM body: Y = A @ B^T + bias, * alpha -------------------
// GBKT=128/DBUF=0: single buffer, half the K-steps -> half the barrier
// rendezvous (Ω) count at equal LDS/occupancy (confirmed r22/r23).
#define BN 128

template<int OUT_F32, int BMT, int BIAS_ROW, int GBKT, int DBUF>
__device__ __forceinline__
void gemm_body(u16t* __restrict__ smem,
               const u16t* __restrict__ A, const u16t* __restrict__ B,
               const float* __restrict__ bias, void* __restrict__ Y,
               int N, int K, float alpha, int m0, int n0)
{
  constexpr int MF = BMT / 32;
  constexpr int COL8 = GBKT / 8;            // 8-u16 column groups per row
  constexpr int KKN = GBKT / 32;            // K=32 MFMA slices per step
  constexpr int IA = BMT * COL8 / 256;      // A gload issues per thread
  constexpr int IB = BN * COL8 / 256;       // B gload issues per thread
  constexpr int TILE = (BMT + BN) * GBKT;   // u16 per buffer

  const int tid = threadIdx.x;
  const int lane = tid & 63;
  const int lr = lane & 15, lg = lane >> 4;
  const int w = tid >> 6;
  const int wm = (w >> 1) * (MF * 16), wn = (w & 1) * 64;

  f32x4 acc[MF][4] = {};
  const int nk = K / GBKT;

  // LDS slot (row, s) holds global col8 (s ^ (row & (COL8-1))) — rule-21 pair
  auto stage = [&](int buf, int kt) {
    u16t* sA = smem + buf * TILE;
    u16t* sB = sA + BMT * GBKT;
#pragma unroll
    for (int i = 0; i < IA; ++i) {
      int c = i * 256 + tid;
      int row = c / COL8, g = (c % COL8) ^ (row & (COL8 - 1));
      gload_lds16(A + (size_t)(m0 + row) * K + kt * GBKT + g * 8, sA + (size_t)c * 8);
    }
#pragma unroll
    for (int i = 0; i < IB; ++i) {
      int c = i * 256 + tid;
      int row = c / COL8, g = (c % COL8) ^ (row & (COL8 - 1));
      gload_lds16(B + (size_t)(n0 + row) * K + kt * GBKT + g * 8, sB + (size_t)c * 8);
    }
  };

  if (DBUF) { stage(0, 0); __syncthreads(); }

  for (int kt = 0; kt < nk; ++kt) {
    const int buf = DBUF ? (kt & 1) : 0;
    if (DBUF) {
      if (kt + 1 < nk) stage(buf ^ 1, kt + 1);
    } else {
      if (kt) __syncthreads();
      stage(0, kt);
      __syncthreads();
    }

    const u16t* sA = smem + buf * TILE;
    const u16t* sB = sA + BMT * GBKT;

#pragma unroll
    for (int kk = 0; kk < KKN; ++kk) {
      short8 af2[MF], bf2[4];
      int s = ((kk * 4 + lg) ^ (lr & (COL8 - 1)));
#pragma unroll
      for (int mf = 0; mf < MF; ++mf)
        af2[mf] = *(const short8*)&sA[(wm + mf * 16 + lr) * GBKT + s * 8];
#pragma unroll
      for (int nf = 0; nf < 4; ++nf)
        bf2[nf] = *(const short8*)&sB[(wn + nf * 16 + lr) * GBKT + s * 8];
      __builtin_amdgcn_s_setprio(1);
#pragma unroll
      for (int mf = 0; mf < MF; ++mf)
#pragma unroll
        for (int nf = 0; nf < 4; ++nf)
          acc[mf][nf] = __builtin_amdgcn_mfma_f32_16x16x32_bf16(af2[mf], bf2[nf], acc[mf][nf], 0, 0, 0);
      __builtin_amdgcn_s_setprio(0);
    }

    if (DBUF && kt + 1 < nk) __syncthreads();
  }

#pragma unroll
  for (int nf = 0; nf < 4; ++nf) {
    int col = n0 + wn + nf * 16 + lr;
    float bvc = BIAS_ROW ? 0.f : bias[col];
#pragma unroll
    for (int mf = 0; mf < MF; ++mf)
#pragma unroll
      for (int r = 0; r < 4; ++r) {
        int row = m0 + wm + mf * 16 + lg * 4 + r;
        float bv = BIAS_ROW ? bias[row] : bvc;
        float v = (acc[mf][nf][r] + bv) * alpha;
        if (OUT_F32) ((float*)Y)[(size_t)row * N + col] = v;
        else         ((u16t*)Y)[(size_t)row * N + col] = f2bf(v);
      }
  }
}

// fused Q/K/V projection: 768 blocks (1D), bijective XCD swizzle (96 blocks/XCD)
#define QSCALE 0.18033688011112042f
__global__ __launch_bounds__(256)
void gemm_qkv(const u16t* __restrict__ xq, const u16t* __restrict__ xk, const u16t* __restrict__ xv,
              const u16t* __restrict__ wq, const u16t* __restrict__ wk, const u16t* __restrict__ wv,
              const float* __restrict__ bq, const float* __restrict__ bk, const float* __restrict__ bv,
              u16t* __restrict__ Qp, u16t* __restrict__ Kp, u16t* __restrict__ Vt)
{
  __shared__ __align__(16) u16t smem[(128 + 128) * 128];  // 64 KB single buffer

  int b = blockIdx.x;
  int wid = (b & 7) * 96 + (b >> 3);
  int z = wid >> 8;
  int rem = wid & 255;
  if (z == 0) {
    gemm_body<0, 128, 0, 128, 0>(smem, xq, wq, bq, Qp, DMODEL, DMODEL, QSCALE, (rem >> 3) * 128, (rem & 7) * BN);
  } else if (z == 1) {
    gemm_body<0, 128, 0, 128, 0>(smem, xk, wk, bk, Kp, DMODEL, DMODEL, 1.0f, (rem >> 3) * 128, (rem & 7) * BN);
  } else {
    gemm_body<0, 128, 1, 128, 0>(smem, wv, xv, bv, Vt, S_LEN, DMODEL, 1.0f, (rem & 7) * 128, (rem >> 3) * BN);
  }
}

__global__ __launch_bounds__(256)
void gemm_o(const u16t* __restrict__ A, const u16t* __restrict__ B,
            const float* __restrict__ bias, float* __restrict__ Y)
{
  __shared__ __align__(16) u16t smem[(64 + 128) * 128];  // 48 KB single buffer

  int b = blockIdx.x;
  int wid = (b & 7) * 64 + (b >> 3);
  int my = wid >> 3, mx = wid & 7;
  gemm_body<1, 64, 0, 128, 0>(smem, A, B, bias, Y, DMODEL, DMODEL, 1.0f, my * 64, mx * BN);
}

// ---------------- flash-style sparse attention ----------------------------------
// T1 XCD swizzle (K/V L2-resident); 4-wave blocks; swapped QK^T; per-lane l;
// gated max reduce. NEW (r24): V single-buffered, staged AFTER the post-PV
// barrier — its L2 latency hides under next tile's QK+softmax. LDS 40->32 KB
// => 5 blocks/CU (+25% TLP) and single-round grid residency (1280 >= 1136).
// Cost: a second (pre-PV) barrier per tile to drain V deposits.
__global__ __launch_bounds__(256)
void attn_kernel(const u16t* __restrict__ Qp, const u16t* __restrict__ Kp,
                 const u16t* __restrict__ Vt, u16t* __restrict__ AO,
                 float* __restrict__ pacc, float* __restrict__ pml)
{
  // 16 (K dbuf) + 8 (V single) + 8 (P) = 32 KB exactly -> 5 blocks/CU
  __shared__ __align__(16) u16t sK[2][64 * 64];
  __shared__ __align__(16) u16t sV[64 * 64];
  __shared__ __align__(16) u16t sP[4][16 * 64];

  const int b = blockIdx.x;                    // 0..1135
  const int wid = (b & 7) * 142 + (b >> 3);    // XCD-contiguous work id
  const int h = wid / 71;
  const int x = wid % 71;                      // 0..70 within head

  const int tid = threadIdx.x, w = tid >> 6, lane = tid & 63;
  const int lr = lane & 15, lg = lane >> 4;

  const bool windowed = (x < 63);
  const int qb = windowed ? (x + 1) : 0;
  const int split = windowed ? 0 : (x - 63);
  const int qw = qb * 64 + w * 16;

  short8 qf[2];
#pragma unroll
  for (int kk = 0; kk < 2; ++kk)
    qf[kk] = *(const short8*)(Qp + (size_t)(qw + lr) * DMODEL + h * DKH + kk * 32 + lg * 8);

  f32x4 acc[4] = {};
  float m_run = -1e30f;   // group-uniform (per q-row = lr group) by induction
  float l_run = 0.f;      // PER-LANE partial sum; reduced once at epilogue

  int lo = 1, nkv;
  if (windowed) {
    lo = (qb - 4 < 1) ? 1 : qb - 4;
    int hi = (qb + 4 > 63) ? 63 : qb + 4;
    nkv = hi - lo + 2;  // {0} ∪ [lo..hi]
  } else {
    nkv = 64 / NSPLIT;
  }

#define KVB(idx) (windowed ? ((idx) == 0 ? 0 : lo + (idx) - 1) : (split * (64 / NSPLIT) + (idx)))

  auto stageK = [&](int buf, int kvb) {
    int kv0 = kvb * 64;
#pragma unroll
    for (int j = 0; j < 2; ++j) {
      int c = tid + j * 256;
      int row = c >> 3, g = (c & 7) ^ (row & 7);
      gload_lds16(Kp + (size_t)(kv0 + row) * DMODEL + h * DKH + g * 8, &sK[buf][c * 8]);
    }
  };
  auto stageV = [&](int kvb) {
    int kv0 = kvb * 64;
#pragma unroll
    for (int j = 0; j < 2; ++j) {
      int c = tid + j * 256;
      int row = c >> 3, g = (c & 7) ^ (row & 7);
      gload_lds16(Vt + (size_t)(h * DKH + row) * S_LEN + kv0 + g * 8, &sV[c * 8]);
    }
  };

  stageK(0, KVB(0));
  stageV(KVB(0));
  __syncthreads();

  for (int idx = 0; idx < nkv; ++idx) {
    const int buf = idx & 1;
    const int kvb = KVB(idx);
    const int kv0 = kvb * 64;

    if (idx + 1 < nkv) stageK(buf ^ 1, KVB(idx + 1));

    // S^T = K Q^T: sacc[nf][r] = S[k = kv0 + nf*16 + lg*4 + r][q = qw + lr]
    f32x4 sacc[4] = {};
    __builtin_amdgcn_s_setprio(1);
#pragma unroll
    for (int kk = 0; kk < 2; ++kk)
#pragma unroll
      for (int nf = 0; nf < 4; ++nf) {
        int s = ((kk * 4 + lg) ^ (lr & 7));
        short8 kf = *(const short8*)&sK[buf][(nf * 16 + lr) * 64 + s * 8];
        sacc[nf] = __builtin_amdgcn_mfma_f32_16x16x32_bf16(kf, qf[kk], sacc[nf], 0, 0, 0);
      }
    __builtin_amdgcn_s_setprio(0);

    // mask: only the two edge tiles can mask, and NEVER the global tile kvb==0
    if (windowed && (kvb == qb + 4 || (kvb == qb - 4 && kvb > 0))) {
      int qg = qw + lr;
#pragma unroll
      for (int nf = 0; nf < 4; ++nf)
#pragma unroll
        for (int r = 0; r < 4; ++r) {
          int sg = kv0 + nf * 16 + lg * 4 + r;
          int diff = qg - sg; if (diff < 0) diff = -diff;
          if (diff > WIN) sacc[nf][r] = -1e30f;
        }
    }

    // per-lane local max (no cross-lane) via max3-friendly triples
    float rm0 = fmaxf(fmaxf(sacc[0][0], sacc[0][1]), sacc[0][2]);
    float rm1 = fmaxf(fmaxf(sacc[0][3], sacc[1][0]), sacc[1][1]);
    float rm2 = fmaxf(fmaxf(sacc[1][2], sacc[1][3]), sacc[2][0]);
    float rm3 = fmaxf(fmaxf(sacc[2][1], sacc[2][2]), sacc[2][3]);
    float rm4 = fmaxf(fmaxf(sacc[3][0], sacc[3][1]), sacc[3][2]);
    float rm = fmaxf(fmaxf(rm0, rm1), fmaxf(fmaxf(rm2, rm3), fmaxf(rm4, sacc[3][3])));

    // gated max-reduce + defer-max (T13): cross-lane work only if a lane's
    // local max jumped by > 11 bits (~8 nats) over the running group max.
    if (!__all(rm <= m_run + 11.0f)) {
      rm = fmaxf(rm, __shfl_xor(rm, 16));
      rm = fmaxf(rm, __shfl_xor(rm, 32));
      float mnew = fmaxf(m_run, rm);
      float corr = exp2f(m_run - mnew);
      m_run = mnew;
      l_run *= corr;
      float cq[4];
#pragma unroll
      for (int r = 0; r < 4; ++r) cq[r] = __shfl(corr, lg * 4 + r);
#pragma unroll
      for (int nf = 0; nf < 4; ++nf)
#pragma unroll
        for (int r = 0; r < 4; ++r) acc[nf][r] *= cq[r];
    }

    float p[4][4];
    float rs = 0.f;
#pragma unroll
    for (int nf = 0; nf < 4; ++nf)
#pragma unroll
      for (int r = 0; r < 4; ++r) {
        float e = exp2f(sacc[nf][r] - m_run);
        p[nf][r] = e;
        rs += e;
      }
    l_run += rs;   // per-lane partial; no per-tile shfl reduce

    // P -> LDS via v_cvt_pk_bf16_f32; stride 64 with XOR-block swizzle
#pragma unroll
    for (int nf = 0; nf < 4; ++nf) {
      unsigned int lo32 = cvtpk(p[nf][0], p[nf][1]);
      unsigned int hi32 = cvtpk(p[nf][2], p[nf][3]);
      int blk = (nf * 2 + (lg >> 1)) ^ (lr & 7);
      *(uint2*)&sP[w][lr * 64 + blk * 8 + (lg & 1) * 4] = make_uint2(lo32, hi32);
    }

    __syncthreads();   // V(idx) deposits drained (pre-PV barrier)

    // O += P V : pf reads block kk*4+lg (same XOR); vf = V^T row d = nf*16+lr
#pragma unroll
    for (int kk = 0; kk < 2; ++kk) {
      short8 pf = *(const short8*)&sP[w][lr * 64 + (((kk * 4 + lg) ^ (lr & 7))) * 8];
      __builtin_amdgcn_s_setprio(1);
#pragma unroll
      for (int nf = 0; nf < 4; ++nf) {
        int s = ((kk * 4 + lg) ^ (lr & 7));
        short8 vf = *(const short8*)&sV[(nf * 16 + lr) * 64 + s * 8];
        acc[nf] = __builtin_amdgcn_mfma_f32_16x16x32_bf16(pf, vf, acc[nf], 0, 0, 0);
      }
      __builtin_amdgcn_s_setprio(0);
    }

    if (idx + 1 < nkv) {
      __syncthreads();          // all waves done reading sV (and sK[buf])
      stageV(KVB(idx + 1));     // overwrite sV; drained by next pre-PV barrier
    }
  }
#undef KVB

  // block-level l reduce: once instead of per-tile
  l_run += __shfl_xor(l_run, 16);
  l_run += __shfl_xor(l_run, 32);

  if (windowed) {
    float lq[4];
#pragma unroll
    for (int r = 0; r < 4; ++r) lq[r] = __shfl(l_run, lg * 4 + r);
#pragma unroll
    for (int nf = 0; nf < 4; ++nf)
#pragma unroll
      for (int r = 0; r < 4; ++r) {
        float v = acc[nf][r] / lq[r];
        AO[(size_t)(qw + lg * 4 + r) * DMODEL + h * DKH + nf * 16 + lr] = f2bf(v);
      }
  } else {
    const int pbase = (h * NSPLIT + split) * 64;
#pragma unroll
    for (int nf = 0; nf < 4; ++nf)
#pragma unroll
      for (int r = 0; r < 4; ++r)
        pacc[(size_t)(pbase + w * 16 + lg * 4 + r) * 64 + nf * 16 + lr] = acc[nf][r];
    if (lane < 16) {
      int bb = (pbase + w * 16 + lane) * 2;
      pml[bb] = m_run;
      pml[bb + 1] = l_run;
    }
  }
}

// ---------------- merge partials for global q rows (exp2 domain) ----------------
__global__ __launch_bounds__(256)
void merge_kernel(const float* __restrict__ pacc, const float* __restrict__ pml,
                  u16t* __restrict__ AO)
{
  const int h = blockIdx.x;
  const int tid = threadIdx.x;
  const int row = tid >> 2;
  const int d0 = (tid & 3) * 16;

  float M = -1e30f;
#pragma unroll
  for (int s = 0; s < NSPLIT; ++s)
    M = fmaxf(M, pml[((h * NSPLIT + s) * 64 + row) * 2]);

  float L = 0.f;
  float o[16];
#pragma unroll
  for (int e = 0; e < 16; ++e) o[e] = 0.f;

#pragma unroll
  for (int s = 0; s < NSPLIT; ++s) {
    int b = ((h * NSPLIT + s) * 64 + row) * 2;
    float sc = exp2f(pml[b] - M);
    L += pml[b + 1] * sc;
    const float4* a = (const float4*)(pacc + ((size_t)(h * NSPLIT + s) * 64 + row) * 64 + d0);
#pragma unroll
    for (int q4 = 0; q4 < 4; ++q4) {
      float4 av = a[q4];
      o[q4 * 4 + 0] += av.x * sc;
      o[q4 * 4 + 1] += av.y * sc;
      o[q4 * 4 + 2] += av.z * sc;
      o[q4 * 4 + 3] += av.w * sc;
    }
  }
  float inv = 1.f / L;
#pragma unroll
  for (int e = 0; e < 16; ++e)
    AO[(size_t)row * DMODEL + h * DKH + d0 + e] = f2bf(o[e] * inv);
}

// ---------------- launch ----------------
extern "C" void kernel_launch(void* const* d_in, const int* in_sizes, int n_in,
                              void* d_out, int out_size, void* d_ws, size_t ws_size,
                              hipStream_t stream) {
  const float* q   = (const float*)d_in[0];
  const float* k   = (const float*)d_in[1];
  const float* v   = (const float*)d_in[2];
  const float* w_q = (const float*)d_in[3];
  const float* b_q = (const float*)d_in[4];
  const float* w_k = (const float*)d_in[5];
  const float* b_k = (const float*)d_in[6];
  const float* w_v = (const float*)d_in[7];
  const float* b_v = (const float*)d_in[8];
  const float* w_o = (const float*)d_in[9];
  const float* b_o = (const float*)d_in[10];

  u16t* ws = (u16t*)d_ws;
  const size_t SZX = (size_t)S_LEN * DMODEL;   // 2^22
  const size_t SZW = (size_t)DMODEL * DMODEL;  // 2^20
  u16t* xq  = ws;
  u16t* xk  = xq + SZX;
  u16t* xv  = xk + SZX;
  u16t* wb0 = xv + SZX;
  u16t* wb1 = wb0 + SZW;
  u16t* wb2 = wb1 + SZW;
  u16t* wb3 = wb2 + SZW;
  u16t* Qp  = wb3 + SZW;
  u16t* Kp  = Qp + SZX;
  u16t* Vt  = Kp + SZX;   // V^T: [NHEADS*DKH][S_LEN]
  u16t* AO  = xk;         // dead after gemm_qkv
  float* pacc = (float*)xq;
  float* pml  = pacc + (size_t)NHEADS * NSPLIT * 64 * 64;

  dim3 blk(256);

  cvt_all<<<(int)((4 * SZW + 3 * SZX) / 1024), blk, 0, stream>>>(
      w_q, w_k, w_v, w_o, q, k, v, wb0, wb1, wb2, wb3, xq, xk, xv);

  gemm_qkv<<<768, blk, 0, stream>>>(xq, xk, xv, wb0, wb1, wb2, b_q, b_k, b_v, Qp, Kp, Vt);

  attn_kernel<<<(63 + NSPLIT) * NHEADS, blk, 0, stream>>>(Qp, Kp, Vt, AO, pacc, pml);
  merge_kernel<<<NHEADS, blk, 0, stream>>>(pacc, pml, AO);

  gemm_o<<<512, blk, 0, stream>>>(AO, wb3, b_o, (float*)d_out);
}